// Round 3
// baseline (1193.534 us; speedup 1.0000x reference)
//
#include <hip/hip_runtime.h>
#include <math.h>

#define NB 8
#define SS 512
#define HH 768
#define NHD 12
#define HDIM 64
#define DWD 300
#define WW 256
#define LL 4

__device__ __forceinline__ float waveReduceSum(float v){
    #pragma unroll
    for(int o=32;o>0;o>>=1) v += __shfl_xor(v,o,64);
    return v;
}

// ---------------- GEMM1: t = tanh(table[ids] @ dt_w + dt_b)  (2048x300x768)
// Blocks 0..15 also zero the keep mask (consumed only after k_cos, 3 kernels later).
__global__ __launch_bounds__(256) void k_embed1(const float* __restrict__ table,
        const int* __restrict__ ids, const float* __restrict__ Wm,
        const float* __restrict__ bias, float* __restrict__ out,
        int* __restrict__ keep){
    if(blockIdx.x < 16){
        int i = blockIdx.x*256 + threadIdx.x;
        if(i < NB*SS) keep[i] = 0;
    }
    const int K=300;
    __shared__ float As[16][68];
    __shared__ float Bs[16][68];
    int bx = blockIdx.x % 12;           // N tile
    int by = blockIdx.x / 12;           // M tile
    int m0 = by*64, n0 = bx*64;
    int t = threadIdx.x;
    int tm = t>>4, tn = t&15;
    int lm = t>>2, lk = (t&3)*4;        // A load coords
    int bj = t&63, bk0 = (t>>6)*4;      // B load coords
    int row_id = ids[m0+lm];
    float acc[4][4] = {};
    for(int k0=0;k0<K;k0+=16){
        #pragma unroll
        for(int e=0;e<4;e++){
            int kk = k0+lk+e;
            As[lk+e][lm] = (kk<K)? table[(size_t)row_id*DWD + kk] : 0.f;
        }
        #pragma unroll
        for(int e=0;e<4;e++){
            int kk = k0+bk0+e;
            Bs[bk0+e][bj] = (kk<K)? Wm[(size_t)kk*HH + n0+bj] : 0.f;
        }
        __syncthreads();
        #pragma unroll
        for(int k=0;k<16;k++){
            float4 a = *(const float4*)&As[k][tm*4];
            float4 b = *(const float4*)&Bs[k][tn*4];
            acc[0][0]+=a.x*b.x; acc[0][1]+=a.x*b.y; acc[0][2]+=a.x*b.z; acc[0][3]+=a.x*b.w;
            acc[1][0]+=a.y*b.x; acc[1][1]+=a.y*b.y; acc[1][2]+=a.y*b.z; acc[1][3]+=a.y*b.w;
            acc[2][0]+=a.z*b.x; acc[2][1]+=a.z*b.y; acc[2][2]+=a.z*b.z; acc[2][3]+=a.z*b.w;
            acc[3][0]+=a.w*b.x; acc[3][1]+=a.w*b.y; acc[3][2]+=a.w*b.z; acc[3][3]+=a.w*b.w;
        }
        __syncthreads();
    }
    #pragma unroll
    for(int i=0;i<4;i++){
        int m = m0 + tm*4 + i;
        int n = n0 + tn*4;
        float4 o;
        o.x = tanhf(acc[i][0] + bias[n+0]);
        o.y = tanhf(acc[i][1] + bias[n+1]);
        o.z = tanhf(acc[i][2] + bias[n+2]);
        o.w = tanhf(acc[i][3] + bias[n+3]);
        *(float4*)&out[(size_t)m*HH + n] = o;
    }
}

// ---------------- GEMM2: we = t @ dr_w + dr_b  (2048x768x768)
__global__ __launch_bounds__(256) void k_embed2(const float* __restrict__ A,
        const float* __restrict__ Wm, const float* __restrict__ bias,
        float* __restrict__ out){
    __shared__ float As[16][68];
    __shared__ float Bs[16][68];
    int bx = blockIdx.x % 12;
    int by = blockIdx.x / 12;
    int m0 = by*64, n0 = bx*64;
    int t = threadIdx.x;
    int tm = t>>4, tn = t&15;
    int lm = t>>2, lk = (t&3)*4;
    int bj = t&63, bk0 = (t>>6)*4;
    float acc[4][4] = {};
    for(int k0=0;k0<HH;k0+=16){
        float4 av = *(const float4*)&A[(size_t)(m0+lm)*HH + k0 + lk];
        As[lk+0][lm]=av.x; As[lk+1][lm]=av.y; As[lk+2][lm]=av.z; As[lk+3][lm]=av.w;
        #pragma unroll
        for(int e=0;e<4;e++)
            Bs[bk0+e][bj] = Wm[(size_t)(k0+bk0+e)*HH + n0 + bj];
        __syncthreads();
        #pragma unroll
        for(int k=0;k<16;k++){
            float4 a = *(const float4*)&As[k][tm*4];
            float4 b = *(const float4*)&Bs[k][tn*4];
            acc[0][0]+=a.x*b.x; acc[0][1]+=a.x*b.y; acc[0][2]+=a.x*b.z; acc[0][3]+=a.x*b.w;
            acc[1][0]+=a.y*b.x; acc[1][1]+=a.y*b.y; acc[1][2]+=a.y*b.z; acc[1][3]+=a.y*b.w;
            acc[2][0]+=a.z*b.x; acc[2][1]+=a.z*b.y; acc[2][2]+=a.z*b.z; acc[2][3]+=a.z*b.w;
            acc[3][0]+=a.w*b.x; acc[3][1]+=a.w*b.y; acc[3][2]+=a.w*b.z; acc[3][3]+=a.w*b.w;
        }
        __syncthreads();
    }
    #pragma unroll
    for(int i=0;i<4;i++){
        int m = m0 + tm*4 + i;
        int n = n0 + tn*4;
        float4 o;
        o.x = acc[i][0] + bias[n+0];
        o.y = acc[i][1] + bias[n+1];
        o.z = acc[i][2] + bias[n+2];
        o.w = acc[i][3] + bias[n+3];
        *(float4*)&out[(size_t)m*HH + n] = o;
    }
}

// ---------------- cos / softmax(L) / mic / keep   (one wave per (b,w))
__global__ __launch_bounds__(256) void k_cos(const float* __restrict__ x,
        const int* __restrict__ wi, const float* __restrict__ we,
        float* __restrict__ sm, int* __restrict__ mic, int* __restrict__ keep){
    int wid = blockIdx.x*4 + (threadIdx.x>>6);
    int lane = threadIdx.x & 63;
    if(wid >= NB*WW) return;
    int b = wid / WW;
    int start = wi[wid*2+0];
    int end   = wi[wid*2+1];
    int n = end - start;
    if(n <= 0) return;
    const float* wer = we + (size_t)wid*HH;
    float wev[12];
    float wn = 0.f;
    #pragma unroll
    for(int i=0;i<12;i++){ float v = wer[lane+64*i]; wev[i]=v; wn += v*v; }
    wn = waveReduceSum(wn);
    float cosv[4];
    #pragma unroll
    for(int l=0;l<4;l++){
        if(l < n){
            const float* xr = x + ((size_t)(b*SS + start + l))*HH;
            float d=0.f, xs=0.f;
            #pragma unroll
            for(int i=0;i<12;i++){ float xv = xr[lane+64*i]; d += xv*wev[i]; xs += xv*xv; }
            d = waveReduceSum(d); xs = waveReduceSum(xs);
            cosv[l] = d / sqrtf(xs*wn);
        } else cosv[l] = -1e9f;
    }
    if(lane == 0){
        float m = fmaxf(fmaxf(cosv[0],cosv[1]),fmaxf(cosv[2],cosv[3]));
        float e0 = (0<n)? expf(cosv[0]-m):0.f;
        float e1 = (1<n)? expf(cosv[1]-m):0.f;
        float e2 = (2<n)? expf(cosv[2]-m):0.f;
        float e3 = (3<n)? expf(cosv[3]-m):0.f;
        float den = e0+e1+e2+e3;
        float inv = 1.f/den;
        sm[wid*4+0] = e0*inv; sm[wid*4+1] = e1*inv;
        sm[wid*4+2] = e2*inv; sm[wid*4+3] = e3*inv;
        int best = 0; float bv = cosv[0];
        if(cosv[1] > bv){bv=cosv[1];best=1;}
        if(cosv[2] > bv){bv=cosv[2];best=2;}
        if(cosv[3] > bv){bv=cosv[3];best=3;}
        mic[wid] = best;
        keep[b*SS + start + best] = 1;
    }
}

// ---------------- bulk copy x -> x_mix
__global__ void k_copy(const float4* __restrict__ in, float4* __restrict__ out, int n){
    int i = blockIdx.x*256 + threadIdx.x;
    if(i < n) out[i] = in[i];
}

// ---------------- per-word mixing: write final x_mix rows for word positions
__global__ __launch_bounds__(256) void k_mix(const float* __restrict__ x,
        const int* __restrict__ wi, const float* __restrict__ we,
        const float* __restrict__ sm, const int* __restrict__ mic_,
        const float* __restrict__ lam, float* __restrict__ xmix){
    int bw = blockIdx.x;
    int b = bw / WW;
    int start = wi[bw*2+0];
    int end   = wi[bw*2+1];
    int n = end - start;
    if(n <= 0) return;
    int mic = mic_[bw];
    float f = expf(lam[0] - 1.f);
    float a = (n>1)? (1.f-f)/(float)(n-1) : (1.f-f);
    const float* wer = we + (size_t)bw*HH;
    float s0 = sm[bw*4+0], s1 = sm[bw*4+1], s2 = sm[bw*4+2], s3 = sm[bw*4+3];
    for(int j=threadIdx.x; j<HH; j+=256){
        float wej = wer[j];
        float v0=0.f,v1=0.f,v2=0.f,v3=0.f;
        if(0<n) v0 = x[((size_t)(b*SS+start+0))*HH+j] + s0*wej;
        if(1<n) v1 = x[((size_t)(b*SS+start+1))*HH+j] + s1*wej;
        if(2<n) v2 = x[((size_t)(b*SS+start+2))*HH+j] + s2*wej;
        if(3<n) v3 = x[((size_t)(b*SS+start+3))*HH+j] + s3*wej;
        float sumx = v0+v1+v2+v3;
        float xm = (mic==0)?v0:(mic==1)?v1:(mic==2)?v2:v3;
        float mm = f*xm + a*(sumx-xm);   // mix_mic
        if(0<n) xmix[((size_t)(b*SS+start+0))*HH+j] = (0==mic)? (n==1? v0 : mm) : ((1.f-a)*v0 + a*xm);
        if(1<n) xmix[((size_t)(b*SS+start+1))*HH+j] = (1==mic)? mm : ((1.f-a)*v1 + a*xm);
        if(2<n) xmix[((size_t)(b*SS+start+2))*HH+j] = (2==mic)? mm : ((1.f-a)*v2 + a*xm);
        if(3<n) xmix[((size_t)(b*SS+start+3))*HH+j] = (3==mic)? mm : ((1.f-a)*v3 + a*xm);
    }
}

// ---------------- q0 projection + r vectors + score consts (per batch)
__global__ __launch_bounds__(256) void k_qr(const float* __restrict__ x,
        const float* __restrict__ qw, const float* __restrict__ qb,
        const float* __restrict__ kw, const float* __restrict__ kb,
        const float* __restrict__ qiw, const float* __restrict__ qib,
        const float* __restrict__ kiw, const float* __restrict__ kib,
        float* __restrict__ r, float* __restrict__ cst){
    int b = blockIdx.x;
    __shared__ float x0[HH];
    __shared__ float q0[HH], qi0[HH];
    int t = threadIdx.x;
    for(int i=t;i<HH;i+=256) x0[i] = x[((size_t)(b*SS))*HH + i];
    __syncthreads();
    for(int j=t;j<HH;j+=256){
        float a1 = qb[j], a2 = qib[j];
        for(int i=0;i<HH;i++){
            float xv = x0[i];
            a1 += xv*qw[(size_t)i*HH+j];
            a2 += xv*qiw[(size_t)i*HH+j];
        }
        q0[j]=a1; qi0[j]=a2;
    }
    __syncthreads();
    for(int idx=t; idx<24*HH; idx+=256){
        int slot = idx/HH, c = idx%HH;
        int h = slot % NHD;
        const float* K = (slot<NHD)? kw : kiw;
        const float* Q = (slot<NHD)? q0 : qi0;
        float a = 0.f;
        #pragma unroll
        for(int j=0;j<HDIM;j++) a += K[(size_t)c*HH + h*HDIM + j]*Q[h*HDIM+j];
        r[((size_t)(b*24+slot))*HH + c] = a;
    }
    if(t < 24){
        int slot = t, h = slot % NHD;
        const float* Kb = (slot<NHD)? kb : kib;
        const float* Q  = (slot<NHD)? q0 : qi0;
        float a = 0.f;
        for(int j=0;j<HDIM;j++) a += Kb[h*HDIM+j]*Q[h*HDIM+j];
        cst[b*24+slot] = a;
    }
}

// ---------------- scores[b,slot,s] = (x_mix[b,s]·r + cst)/8, keep-mask slots>=12
__global__ __launch_bounds__(256) void k_scores(const float* __restrict__ xmix,
        const float* __restrict__ r, const float* __restrict__ cst,
        const int* __restrict__ keep, float* __restrict__ scores){
    int bs = blockIdx.x;
    int b = bs >> 9, s = bs & 511;
    __shared__ float xr[HH];
    for(int i=threadIdx.x;i<HH;i+=256) xr[i] = xmix[(size_t)bs*HH + i];
    __syncthreads();
    int wv = threadIdx.x>>6, lane = threadIdx.x&63;
    int kp = keep[b*SS + s];
    #pragma unroll
    for(int q=0;q<6;q++){
        int slot = wv*6 + q;
        const float* rr = r + ((size_t)(b*24+slot))*HH;
        float d = 0.f;
        #pragma unroll
        for(int i=0;i<12;i++) d += xr[lane+64*i]*rr[lane+64*i];
        d = waveReduceSum(d);
        if(lane==0){
            float sc = (d + cst[b*24+slot])*0.125f;
            if(slot>=12 && !kp) sc = -1e30f;
            scores[((size_t)(b*24+slot))*SS + s] = sc;
        }
    }
}

// ---------------- softmax over S per (b,slot) row, in place
__global__ __launch_bounds__(256) void k_softmax(float* __restrict__ scores){
    int row = blockIdx.x;
    float* p = scores + (size_t)row*SS;
    int t = threadIdx.x;
    __shared__ float red[256];
    float v0 = p[t], v1 = p[t+256];
    red[t] = fmaxf(v0,v1); __syncthreads();
    for(int o=128;o>0;o>>=1){ if(t<o) red[t] = fmaxf(red[t],red[t+o]); __syncthreads(); }
    float m = red[0]; __syncthreads();
    float e0 = expf(v0-m), e1 = expf(v1-m);
    red[t] = e0+e1; __syncthreads();
    for(int o=128;o>0;o>>=1){ if(t<o) red[t] += red[t+o]; __syncthreads(); }
    float inv = 1.f/red[0];
    p[t] = e0*inv; p[t+256] = e1*inv;
}

// ---------------- partial weighted row-sums c over s-chunks of 64
__global__ __launch_bounds__(256) void k_cpart(const float* __restrict__ p,
        const float* __restrict__ xmix, float* __restrict__ cpart){
    int b = blockIdx.x >> 3, cc = blockIdx.x & 7;
    int s0 = cc*64;
    __shared__ float ps[24][64];
    int t = threadIdx.x;
    for(int i=t;i<24*64;i+=256){
        int slot=i>>6, ss=i&63;
        ps[slot][ss] = p[((size_t)(b*24+slot))*SS + s0 + ss];
    }
    __syncthreads();
    float acc[24][3];
    #pragma unroll
    for(int sl=0;sl<24;sl++){ acc[sl][0]=0.f; acc[sl][1]=0.f; acc[sl][2]=0.f; }
    for(int s=0;s<64;s++){
        size_t base = ((size_t)(b*SS + s0 + s))*HH;
        float xv0 = xmix[base + t];
        float xv1 = xmix[base + t + 256];
        float xv2 = xmix[base + t + 512];
        #pragma unroll
        for(int sl=0;sl<24;sl++){
            float pv = ps[sl][s];
            acc[sl][0] += pv*xv0; acc[sl][1] += pv*xv1; acc[sl][2] += pv*xv2;
        }
    }
    #pragma unroll
    for(int sl=0;sl<24;sl++){
        size_t base = (((size_t)(b*8+cc))*24 + sl)*HH;
        cpart[base + t]       = acc[sl][0];
        cpart[base + t + 256] = acc[sl][1];
        cpart[base + t + 512] = acc[sl][2];
    }
}

// ---------------- reduce cpart over chunks -> cg
__global__ void k_credux(const float* __restrict__ cpart, float* __restrict__ cg){
    int idx = blockIdx.x*256 + threadIdx.x;
    if(idx >= NB*24*HH) return;
    int b = idx / (24*HH), rest = idx % (24*HH);
    float s = 0.f;
    for(int cc=0;cc<8;cc++) s += cpart[((size_t)(b*8+cc))*(24*HH) + rest];
    cg[idx] = s;
}

// ---------------- final: h1/h2 -> fus -> pooled -> logits (per batch)
__global__ __launch_bounds__(256) void k_final(const float* __restrict__ cg,
        const float* __restrict__ vw, const float* __restrict__ vb,
        const float* __restrict__ viw, const float* __restrict__ vib,
        const float* __restrict__ mu_,
        const float* __restrict__ fw, const float* __restrict__ fb,
        const float* __restrict__ dw, const float* __restrict__ db,
        const float* __restrict__ cw, const float* __restrict__ cb,
        float* __restrict__ out){
    int b = blockIdx.x;
    __shared__ float g[HH], fus[HH], pooled[HH];
    __shared__ float red[256];
    float mu = mu_[0];
    int t = threadIdx.x;
    for(int j=t;j<HH;j+=256){
        int h = j >> 6;
        const float* c1 = cg + ((size_t)(b*24+h))*HH;
        const float* c2 = cg + ((size_t)(b*24+12+h))*HH;
        float a1 = vb[j], a2 = vib[j];
        for(int i=0;i<HH;i++){
            a1 += c1[i]*vw[(size_t)i*HH+j];
            a2 += c2[i]*viw[(size_t)i*HH+j];
        }
        g[j] = mu*a1 + (1.f-mu)*a2;
    }
    __syncthreads();
    for(int j=t;j<HH;j+=256){
        float a = fb[j];
        for(int i=0;i<HH;i++) a += g[i]*fw[(size_t)i*HH+j];
        fus[j] = tanhf(a);
    }
    __syncthreads();
    for(int j=t;j<HH;j+=256){
        float a = db[j];
        for(int i=0;i<HH;i++) a += fus[i]*dw[(size_t)i*HH+j];
        pooled[j] = tanhf(a);
    }
    __syncthreads();
    float p0=0.f, p1=0.f;
    for(int i=t;i<HH;i+=256){ p0 += pooled[i]*cw[i*2+0]; p1 += pooled[i]*cw[i*2+1]; }
    red[t]=p0; __syncthreads();
    for(int o=128;o>0;o>>=1){ if(t<o) red[t]+=red[t+o]; __syncthreads(); }
    if(t==0) out[b*2+0] = red[0]+cb[0];
    __syncthreads();
    red[t]=p1; __syncthreads();
    for(int o=128;o>0;o>>=1){ if(t<o) red[t]+=red[t+o]; __syncthreads(); }
    if(t==0) out[b*2+1] = red[0]+cb[1];
}

extern "C" void kernel_launch(void* const* d_in, const int* in_sizes, int n_in,
                              void* d_out, int out_size, void* d_ws, size_t ws_size,
                              hipStream_t stream) {
    const float* x          = (const float*)d_in[0];
    const int*   word_ids   = (const int*)  d_in[1];
    const int*   word_index = (const int*)  d_in[2];
    const float* table      = (const float*)d_in[3];
    const float* lam        = (const float*)d_in[4];
    const float* mu         = (const float*)d_in[5];
    const float* dt_w = (const float*)d_in[6];
    const float* dt_b = (const float*)d_in[7];
    const float* dr_w = (const float*)d_in[8];
    const float* dr_b = (const float*)d_in[9];
    const float* q_w  = (const float*)d_in[10];
    const float* q_b  = (const float*)d_in[11];
    const float* k_w  = (const float*)d_in[12];
    const float* k_b  = (const float*)d_in[13];
    const float* v_w  = (const float*)d_in[14];
    const float* v_b  = (const float*)d_in[15];
    const float* qi_w = (const float*)d_in[16];
    const float* qi_b = (const float*)d_in[17];
    const float* ki_w = (const float*)d_in[18];
    const float* ki_b = (const float*)d_in[19];
    const float* vi_w = (const float*)d_in[20];
    const float* vi_b = (const float*)d_in[21];
    const float* fus_w = (const float*)d_in[22];
    const float* fus_b = (const float*)d_in[23];
    const float* dense_w = (const float*)d_in[24];
    const float* dense_b = (const float*)d_in[25];
    const float* cls_w = (const float*)d_in[26];
    const float* cls_b = (const float*)d_in[27];
    float* out = (float*)d_out;

    char* w = (char*)d_ws;
    float* xmix   = (float*)(w + 0);          // 12,582,912 B (tbuf aliases here early)
    float* tbuf   = (float*)(w + 0);          // 6,291,456 B, dead before k_copy
    float* we     = (float*)(w + 12582912);   //  6,291,456 B
    float* scores = (float*)(w + 18874368);   //    393,216 B
    float* r      = (float*)(w + 19267584);   //    589,824 B
    float* cst    = (float*)(w + 19857408);   //      1,024 B
    float* sm     = (float*)(w + 19858432);   //     32,768 B
    int*   mic    = (int*)  (w + 19891200);   //      8,192 B
    int*   keep   = (int*)  (w + 19899392);   //     16,384 B
    float* cg     = (float*)(w + 19915776);   //    589,824 B
    float* cpart  = (float*)(w + 20505600);   //  4,718,592 B  -> total 25,224,192 B
    (void)ws_size; (void)in_sizes; (void)n_in; (void)out_size;

    // word embeddings (k_embed1 also zeroes keep in blocks 0..15)
    k_embed1<<<384, 256, 0, stream>>>(table, word_ids, dt_w, dt_b, tbuf, keep);
    k_embed2<<<384, 256, 0, stream>>>(tbuf, dr_w, dr_b, we);
    // cosine/softmax/mic + keep-mask scatter
    k_cos<<<512, 256, 0, stream>>>(x, word_index, we, sm, mic, keep);
    // x_mix construction (k_copy overwrites the tbuf alias only after tbuf is dead)
    k_copy<<<3072, 256, 0, stream>>>((const float4*)x, (float4*)xmix, NB*SS*HH/4);
    k_mix<<<NB*WW, 256, 0, stream>>>(x, word_index, we, sm, mic, lam, xmix);
    // attention (query row 0 only, rank-1 trick)
    k_qr<<<NB, 256, 0, stream>>>(x, q_w, q_b, k_w, k_b, qi_w, qi_b, ki_w, ki_b, r, cst);
    k_scores<<<NB*SS, 256, 0, stream>>>(xmix, r, cst, keep, scores);
    k_softmax<<<NB*24, 256, 0, stream>>>(scores);
    k_cpart<<<NB*8, 256, 0, stream>>>(scores, xmix, cpart);
    k_credux<<<(NB*24*HH+255)/256, 256, 0, stream>>>(cpart, cg);
    // epilogue chain
    k_final<<<NB, 256, 0, stream>>>(cg, v_w, v_b, vi_w, vi_b, mu,
                                    fus_w, fus_b, dense_w, dense_b, cls_w, cls_b, out);
}

// Round 4
// 610.119 us; speedup vs baseline: 1.9562x; 1.9562x over previous
//
#include <hip/hip_runtime.h>
#include <math.h>

#define NB 8
#define SS 512
#define HH 768
#define NHD 12
#define HDIM 64
#define DWD 300
#define WW 256
#define LL 4
#define KC 6          // K-chunks for 768-deep matvecs (128 each)

__device__ __forceinline__ float waveReduceSum(float v){
    #pragma unroll
    for(int o=32;o>0;o>>=1) v += __shfl_xor(v,o,64);
    return v;
}

// ---------------- GEMM1: t = tanh(table[ids] @ dt_w + dt_b)  (2048x300x768)
// Blocks 0..15 also zero the keep mask (consumed only after k_cos).
__global__ __launch_bounds__(256) void k_embed1(const float* __restrict__ table,
        const int* __restrict__ ids, const float* __restrict__ Wm,
        const float* __restrict__ bias, float* __restrict__ out,
        int* __restrict__ keep){
    if(blockIdx.x < 16){
        int i = blockIdx.x*256 + threadIdx.x;
        if(i < NB*SS) keep[i] = 0;
    }
    const int K=300;
    __shared__ float As[16][68];
    __shared__ float Bs[16][68];
    int bx = blockIdx.x % 12;           // N tile
    int by = blockIdx.x / 12;           // M tile
    int m0 = by*64, n0 = bx*64;
    int t = threadIdx.x;
    int tm = t>>4, tn = t&15;
    int lm = t>>2, lk = (t&3)*4;        // A load coords
    int bj = t&63, bk0 = (t>>6)*4;      // B load coords
    int row_id = ids[m0+lm];
    float acc[4][4] = {};
    for(int k0=0;k0<K;k0+=16){
        #pragma unroll
        for(int e=0;e<4;e++){
            int kk = k0+lk+e;
            As[lk+e][lm] = (kk<K)? table[(size_t)row_id*DWD + kk] : 0.f;
        }
        #pragma unroll
        for(int e=0;e<4;e++){
            int kk = k0+bk0+e;
            Bs[bk0+e][bj] = (kk<K)? Wm[(size_t)kk*HH + n0+bj] : 0.f;
        }
        __syncthreads();
        #pragma unroll
        for(int k=0;k<16;k++){
            float4 a = *(const float4*)&As[k][tm*4];
            float4 b = *(const float4*)&Bs[k][tn*4];
            acc[0][0]+=a.x*b.x; acc[0][1]+=a.x*b.y; acc[0][2]+=a.x*b.z; acc[0][3]+=a.x*b.w;
            acc[1][0]+=a.y*b.x; acc[1][1]+=a.y*b.y; acc[1][2]+=a.y*b.z; acc[1][3]+=a.y*b.w;
            acc[2][0]+=a.z*b.x; acc[2][1]+=a.z*b.y; acc[2][2]+=a.z*b.z; acc[2][3]+=a.z*b.w;
            acc[3][0]+=a.w*b.x; acc[3][1]+=a.w*b.y; acc[3][2]+=a.w*b.z; acc[3][3]+=a.w*b.w;
        }
        __syncthreads();
    }
    #pragma unroll
    for(int i=0;i<4;i++){
        int m = m0 + tm*4 + i;
        int n = n0 + tn*4;
        float4 o;
        o.x = tanhf(acc[i][0] + bias[n+0]);
        o.y = tanhf(acc[i][1] + bias[n+1]);
        o.z = tanhf(acc[i][2] + bias[n+2]);
        o.w = tanhf(acc[i][3] + bias[n+3]);
        *(float4*)&out[(size_t)m*HH + n] = o;
    }
}

// ---------------- GEMM2: we = t @ dr_w + dr_b  (2048x768x768)
__global__ __launch_bounds__(256) void k_embed2(const float* __restrict__ A,
        const float* __restrict__ Wm, const float* __restrict__ bias,
        float* __restrict__ out){
    __shared__ float As[16][68];
    __shared__ float Bs[16][68];
    int bx = blockIdx.x % 12;
    int by = blockIdx.x / 12;
    int m0 = by*64, n0 = bx*64;
    int t = threadIdx.x;
    int tm = t>>4, tn = t&15;
    int lm = t>>2, lk = (t&3)*4;
    int bj = t&63, bk0 = (t>>6)*4;
    float acc[4][4] = {};
    for(int k0=0;k0<HH;k0+=16){
        float4 av = *(const float4*)&A[(size_t)(m0+lm)*HH + k0 + lk];
        As[lk+0][lm]=av.x; As[lk+1][lm]=av.y; As[lk+2][lm]=av.z; As[lk+3][lm]=av.w;
        #pragma unroll
        for(int e=0;e<4;e++)
            Bs[bk0+e][bj] = Wm[(size_t)(k0+bk0+e)*HH + n0 + bj];
        __syncthreads();
        #pragma unroll
        for(int k=0;k<16;k++){
            float4 a = *(const float4*)&As[k][tm*4];
            float4 b = *(const float4*)&Bs[k][tn*4];
            acc[0][0]+=a.x*b.x; acc[0][1]+=a.x*b.y; acc[0][2]+=a.x*b.z; acc[0][3]+=a.x*b.w;
            acc[1][0]+=a.y*b.x; acc[1][1]+=a.y*b.y; acc[1][2]+=a.y*b.z; acc[1][3]+=a.y*b.w;
            acc[2][0]+=a.z*b.x; acc[2][1]+=a.z*b.y; acc[2][2]+=a.z*b.z; acc[2][3]+=a.z*b.w;
            acc[3][0]+=a.w*b.x; acc[3][1]+=a.w*b.y; acc[3][2]+=a.w*b.z; acc[3][3]+=a.w*b.w;
        }
        __syncthreads();
    }
    #pragma unroll
    for(int i=0;i<4;i++){
        int m = m0 + tm*4 + i;
        int n = n0 + tn*4;
        float4 o;
        o.x = acc[i][0] + bias[n+0];
        o.y = acc[i][1] + bias[n+1];
        o.z = acc[i][2] + bias[n+2];
        o.w = acc[i][3] + bias[n+3];
        *(float4*)&out[(size_t)m*HH + n] = o;
    }
}

// ---------------- cos / softmax(L) / mic / keep   (one wave per (b,w))
__global__ __launch_bounds__(256) void k_cos(const float* __restrict__ x,
        const int* __restrict__ wi, const float* __restrict__ we,
        float* __restrict__ sm, int* __restrict__ mic, int* __restrict__ keep){
    int wid = blockIdx.x*4 + (threadIdx.x>>6);
    int lane = threadIdx.x & 63;
    if(wid >= NB*WW) return;
    int b = wid / WW;
    int start = wi[wid*2+0];
    int end   = wi[wid*2+1];
    int n = end - start;
    if(n <= 0) return;
    const float* wer = we + (size_t)wid*HH;
    float wev[12];
    float wn = 0.f;
    #pragma unroll
    for(int i=0;i<12;i++){ float v = wer[lane+64*i]; wev[i]=v; wn += v*v; }
    wn = waveReduceSum(wn);
    float cosv[4];
    #pragma unroll
    for(int l=0;l<4;l++){
        if(l < n){
            const float* xr = x + ((size_t)(b*SS + start + l))*HH;
            float d=0.f, xs=0.f;
            #pragma unroll
            for(int i=0;i<12;i++){ float xv = xr[lane+64*i]; d += xv*wev[i]; xs += xv*xv; }
            d = waveReduceSum(d); xs = waveReduceSum(xs);
            cosv[l] = d / sqrtf(xs*wn);
        } else cosv[l] = -1e9f;
    }
    if(lane == 0){
        float m = fmaxf(fmaxf(cosv[0],cosv[1]),fmaxf(cosv[2],cosv[3]));
        float e0 = (0<n)? expf(cosv[0]-m):0.f;
        float e1 = (1<n)? expf(cosv[1]-m):0.f;
        float e2 = (2<n)? expf(cosv[2]-m):0.f;
        float e3 = (3<n)? expf(cosv[3]-m):0.f;
        float den = e0+e1+e2+e3;
        float inv = 1.f/den;
        sm[wid*4+0] = e0*inv; sm[wid*4+1] = e1*inv;
        sm[wid*4+2] = e2*inv; sm[wid*4+3] = e3*inv;
        int best = 0; float bv = cosv[0];
        if(cosv[1] > bv){bv=cosv[1];best=1;}
        if(cosv[2] > bv){bv=cosv[2];best=2;}
        if(cosv[3] > bv){bv=cosv[3];best=3;}
        mic[wid] = best;
        keep[b*SS + start + best] = 1;
    }
}

// ---------------- bulk copy x -> x_mix
__global__ void k_copy(const float4* __restrict__ in, float4* __restrict__ out, int n){
    int i = blockIdx.x*256 + threadIdx.x;
    if(i < n) out[i] = in[i];
}

// ---------------- per-word mixing: write final x_mix rows for word positions
__global__ __launch_bounds__(256) void k_mix(const float* __restrict__ x,
        const int* __restrict__ wi, const float* __restrict__ we,
        const float* __restrict__ sm, const int* __restrict__ mic_,
        const float* __restrict__ lam, float* __restrict__ xmix){
    int bw = blockIdx.x;
    int b = bw / WW;
    int start = wi[bw*2+0];
    int end   = wi[bw*2+1];
    int n = end - start;
    if(n <= 0) return;
    int mic = mic_[bw];
    float f = expf(lam[0] - 1.f);
    float a = (n>1)? (1.f-f)/(float)(n-1) : (1.f-f);
    const float* wer = we + (size_t)bw*HH;
    float s0 = sm[bw*4+0], s1 = sm[bw*4+1], s2 = sm[bw*4+2], s3 = sm[bw*4+3];
    for(int j=threadIdx.x; j<HH; j+=256){
        float wej = wer[j];
        float v0=0.f,v1=0.f,v2=0.f,v3=0.f;
        if(0<n) v0 = x[((size_t)(b*SS+start+0))*HH+j] + s0*wej;
        if(1<n) v1 = x[((size_t)(b*SS+start+1))*HH+j] + s1*wej;
        if(2<n) v2 = x[((size_t)(b*SS+start+2))*HH+j] + s2*wej;
        if(3<n) v3 = x[((size_t)(b*SS+start+3))*HH+j] + s3*wej;
        float sumx = v0+v1+v2+v3;
        float xm = (mic==0)?v0:(mic==1)?v1:(mic==2)?v2:v3;
        float mm = f*xm + a*(sumx-xm);   // mix_mic
        if(0<n) xmix[((size_t)(b*SS+start+0))*HH+j] = (0==mic)? (n==1? v0 : mm) : ((1.f-a)*v0 + a*xm);
        if(1<n) xmix[((size_t)(b*SS+start+1))*HH+j] = (1==mic)? mm : ((1.f-a)*v1 + a*xm);
        if(2<n) xmix[((size_t)(b*SS+start+2))*HH+j] = (2==mic)? mm : ((1.f-a)*v2 + a*xm);
        if(3<n) xmix[((size_t)(b*SS+start+3))*HH+j] = (3==mic)? mm : ((1.f-a)*v3 + a*xm);
    }
}

// ---------------- q0/qi0 partials: qpart[kc][b][2][768]   grid 8*3*6=144
__global__ __launch_bounds__(256) void k_q(const float* __restrict__ x,
        const float* __restrict__ qw, const float* __restrict__ qiw,
        float* __restrict__ qpart){
    int kc = blockIdx.x % KC;
    int jt = (blockIdx.x/KC) % 3;
    int b  = blockIdx.x / (KC*3);
    int j = jt*256 + threadIdx.x;
    const float* x0 = x + (size_t)b*SS*HH;   // seq position 0 (never inside a word)
    int i0 = kc*128;
    float a1=0.f, a2=0.f;
    for(int i=i0;i<i0+128;i++){
        float xv = x0[i];
        a1 += xv*qw[(size_t)i*HH+j];
        a2 += xv*qiw[(size_t)i*HH+j];
    }
    qpart[(((size_t)kc*NB + b)*2 + 0)*HH + j] = a1;
    qpart[(((size_t)kc*NB + b)*2 + 1)*HH + j] = a2;
}

// ---------------- reduce q partials + biases, compute cst   grid 8
__global__ __launch_bounds__(256) void k_qred(const float* __restrict__ qpart,
        const float* __restrict__ qb, const float* __restrict__ qib,
        const float* __restrict__ kb, const float* __restrict__ kib,
        float* __restrict__ q0g, float* __restrict__ cst){
    int b = blockIdx.x;
    __shared__ float q0s[HH], qi0s[HH];
    int t = threadIdx.x;
    for(int j=t;j<HH;j+=256){
        float a1=qb[j], a2=qib[j];
        #pragma unroll
        for(int kc=0;kc<KC;kc++){
            a1 += qpart[(((size_t)kc*NB+b)*2+0)*HH+j];
            a2 += qpart[(((size_t)kc*NB+b)*2+1)*HH+j];
        }
        q0s[j]=a1; qi0s[j]=a2;
        q0g[((size_t)b*2+0)*HH+j]=a1;
        q0g[((size_t)b*2+1)*HH+j]=a2;
    }
    __syncthreads();
    if(t<24){
        int slot=t, h=slot%NHD;
        const float* Kb = (slot<NHD)? kb:kib;
        const float* Q  = (slot<NHD)? q0s:qi0s;
        float a=0.f;
        for(int j=0;j<HDIM;j++) a += Kb[h*HDIM+j]*Q[h*HDIM+j];
        cst[b*24+slot]=a;
    }
}

// ---------------- r[b][slot][c] = sum_j kw[c][h*64+j]*q0[h*64+j]   grid 8*24*3=576
__global__ __launch_bounds__(256) void k_r(const float* __restrict__ q0g,
        const float* __restrict__ kw, const float* __restrict__ kiw,
        float* __restrict__ r){
    int ct = blockIdx.x % 3;
    int slot = (blockIdx.x/3) % 24;
    int b = blockIdx.x / 72;
    int h = slot % NHD;
    __shared__ float qs[HDIM];
    const float* Q = q0g + ((size_t)b*2 + (slot<NHD?0:1))*HH + h*HDIM;
    if(threadIdx.x<HDIM) qs[threadIdx.x] = Q[threadIdx.x];
    __syncthreads();
    const float* K = (slot<NHD)? kw : kiw;
    int c = ct*256 + threadIdx.x;
    const float4* K4 = (const float4*)(K + (size_t)c*HH + h*HDIM);
    const float4* q4 = (const float4*)qs;
    float a=0.f;
    #pragma unroll
    for(int j=0;j<16;j++){
        float4 kv=K4[j], qv=q4[j];
        a += kv.x*qv.x + kv.y*qv.y + kv.z*qv.z + kv.w*qv.w;
    }
    r[((size_t)(b*24+slot))*HH + c] = a;
}

// ---------------- scores[b,slot,s] = (x_mix[b,s]·r + cst)/8, keep-mask slots>=12
__global__ __launch_bounds__(256) void k_scores(const float* __restrict__ xmix,
        const float* __restrict__ r, const float* __restrict__ cst,
        const int* __restrict__ keep, float* __restrict__ scores){
    int bs = blockIdx.x;
    int b = bs >> 9, s = bs & 511;
    __shared__ float xr[HH];
    for(int i=threadIdx.x;i<HH;i+=256) xr[i] = xmix[(size_t)bs*HH + i];
    __syncthreads();
    int wv = threadIdx.x>>6, lane = threadIdx.x&63;
    int kp = keep[b*SS + s];
    #pragma unroll
    for(int q=0;q<6;q++){
        int slot = wv*6 + q;
        const float* rr = r + ((size_t)(b*24+slot))*HH;
        float d = 0.f;
        #pragma unroll
        for(int i=0;i<12;i++) d += xr[lane+64*i]*rr[lane+64*i];
        d = waveReduceSum(d);
        if(lane==0){
            float sc = (d + cst[b*24+slot])*0.125f;
            if(slot>=12 && !kp) sc = -1e30f;
            scores[((size_t)(b*24+slot))*SS + s] = sc;
        }
    }
}

// ---------------- softmax over S per (b,slot) row, in place
__global__ __launch_bounds__(256) void k_softmax(float* __restrict__ scores){
    int row = blockIdx.x;
    float* p = scores + (size_t)row*SS;
    int t = threadIdx.x;
    __shared__ float red[256];
    float v0 = p[t], v1 = p[t+256];
    red[t] = fmaxf(v0,v1); __syncthreads();
    for(int o=128;o>0;o>>=1){ if(t<o) red[t] = fmaxf(red[t],red[t+o]); __syncthreads(); }
    float m = red[0]; __syncthreads();
    float e0 = expf(v0-m), e1 = expf(v1-m);
    red[t] = e0+e1; __syncthreads();
    for(int o=128;o>0;o>>=1){ if(t<o) red[t] += red[t+o]; __syncthreads(); }
    float inv = 1.f/red[0];
    p[t] = e0*inv; p[t+256] = e1*inv;
}

// ---------------- partial weighted row-sums c over s-chunks of 64
__global__ __launch_bounds__(256) void k_cpart(const float* __restrict__ p,
        const float* __restrict__ xmix, float* __restrict__ cpart){
    int b = blockIdx.x >> 3, cc = blockIdx.x & 7;
    int s0 = cc*64;
    __shared__ float ps[24][64];
    int t = threadIdx.x;
    for(int i=t;i<24*64;i+=256){
        int slot=i>>6, ss=i&63;
        ps[slot][ss] = p[((size_t)(b*24+slot))*SS + s0 + ss];
    }
    __syncthreads();
    float acc[24][3];
    #pragma unroll
    for(int sl=0;sl<24;sl++){ acc[sl][0]=0.f; acc[sl][1]=0.f; acc[sl][2]=0.f; }
    for(int s=0;s<64;s++){
        size_t base = ((size_t)(b*SS + s0 + s))*HH;
        float xv0 = xmix[base + t];
        float xv1 = xmix[base + t + 256];
        float xv2 = xmix[base + t + 512];
        #pragma unroll
        for(int sl=0;sl<24;sl++){
            float pv = ps[sl][s];
            acc[sl][0] += pv*xv0; acc[sl][1] += pv*xv1; acc[sl][2] += pv*xv2;
        }
    }
    #pragma unroll
    for(int sl=0;sl<24;sl++){
        size_t base = (((size_t)(b*8+cc))*24 + sl)*HH;
        cpart[base + t]       = acc[sl][0];
        cpart[base + t + 256] = acc[sl][1];
        cpart[base + t + 512] = acc[sl][2];
    }
}

// ---------------- reduce cpart over chunks -> cg
__global__ void k_credux(const float* __restrict__ cpart, float* __restrict__ cg){
    int idx = blockIdx.x*256 + threadIdx.x;
    if(idx >= NB*24*HH) return;
    int b = idx / (24*HH), rest = idx % (24*HH);
    float s = 0.f;
    for(int cc=0;cc<8;cc++) s += cpart[((size_t)(b*8+cc))*(24*HH) + rest];
    cg[idx] = s;
}

// ---------------- stage A partials: mu*h1 + (1-mu)*h2 (no bias)   grid 144
__global__ __launch_bounds__(256) void k_finA(const float* __restrict__ cg,
        const float* __restrict__ vw, const float* __restrict__ viw,
        const float* __restrict__ mu_, float* __restrict__ part){
    int kc = blockIdx.x % KC;
    int jt = (blockIdx.x/KC) % 3;
    int b  = blockIdx.x / (KC*3);
    int j = jt*256 + threadIdx.x;
    int h = j >> 6;                       // wave-uniform (j aligned to 64)
    float mu = mu_[0];
    const float* c1 = cg + ((size_t)(b*24+h))*HH;
    const float* c2 = cg + ((size_t)(b*24+12+h))*HH;
    int i0 = kc*128;
    float a1=0.f, a2=0.f;
    for(int i=i0;i<i0+128;i++){
        a1 += c1[i]*vw[(size_t)i*HH+j];
        a2 += c2[i]*viw[(size_t)i*HH+j];
    }
    part[((size_t)kc*NB+b)*HH + j] = mu*a1 + (1.f-mu)*a2;
}

// ---------------- g = sum partials + mu*vb+(1-mu)*vib   grid 24
__global__ void k_redG(const float* __restrict__ part, const float* __restrict__ vb,
        const float* __restrict__ vib, const float* __restrict__ mu_,
        float* __restrict__ g){
    int idx = blockIdx.x*256+threadIdx.x;
    if(idx >= NB*HH) return;
    int b=idx/HH, j=idx%HH;
    float mu=mu_[0];
    float s = mu*vb[j] + (1.f-mu)*vib[j];
    #pragma unroll
    for(int kc=0;kc<KC;kc++) s += part[((size_t)kc*NB+b)*HH+j];
    g[idx]=s;
}

// ---------------- stage B partials: g @ fus_w   grid 144
__global__ __launch_bounds__(256) void k_finB(const float* __restrict__ g,
        const float* __restrict__ fw, float* __restrict__ part){
    int kc = blockIdx.x % KC;
    int jt = (blockIdx.x/KC) % 3;
    int b  = blockIdx.x / (KC*3);
    int j = jt*256 + threadIdx.x;
    const float* gr = g + (size_t)b*HH;
    int i0 = kc*128;
    float a=0.f;
    for(int i=i0;i<i0+128;i++) a += gr[i]*fw[(size_t)i*HH+j];
    part[((size_t)kc*NB+b)*HH + j] = a;
}

// ---------------- fus = tanh(sum partials + fb)   grid 24
__global__ void k_redF(const float* __restrict__ part, const float* __restrict__ fb,
        float* __restrict__ fus){
    int idx = blockIdx.x*256+threadIdx.x;
    if(idx >= NB*HH) return;
    int b=idx/HH, j=idx%HH;
    float s = fb[j];
    #pragma unroll
    for(int kc=0;kc<KC;kc++) s += part[((size_t)kc*NB+b)*HH+j];
    fus[idx]=tanhf(s);
}

// ---------------- stage C partials: fus @ dense_w   grid 144
__global__ __launch_bounds__(256) void k_finC(const float* __restrict__ fus,
        const float* __restrict__ dw, float* __restrict__ part){
    int kc = blockIdx.x % KC;
    int jt = (blockIdx.x/KC) % 3;
    int b  = blockIdx.x / (KC*3);
    int j = jt*256 + threadIdx.x;
    const float* fr = fus + (size_t)b*HH;
    int i0 = kc*128;
    float a=0.f;
    for(int i=i0;i<i0+128;i++) a += fr[i]*dw[(size_t)i*HH+j];
    part[((size_t)kc*NB+b)*HH + j] = a;
}

// ---------------- pooled = tanh(sum + db); logits = pooled @ cls + cb   grid 8
__global__ __launch_bounds__(256) void k_finD(const float* __restrict__ part,
        const float* __restrict__ db, const float* __restrict__ cw,
        const float* __restrict__ cb, float* __restrict__ out){
    int b = blockIdx.x;
    int t = threadIdx.x;
    __shared__ float pooled[HH];
    __shared__ float red[256];
    for(int j=t;j<HH;j+=256){
        float s = db[j];
        #pragma unroll
        for(int kc=0;kc<KC;kc++) s += part[((size_t)kc*NB+b)*HH+j];
        pooled[j] = tanhf(s);
    }
    __syncthreads();
    float p0=0.f, p1=0.f;
    for(int i=t;i<HH;i+=256){ p0 += pooled[i]*cw[i*2+0]; p1 += pooled[i]*cw[i*2+1]; }
    red[t]=p0; __syncthreads();
    for(int o=128;o>0;o>>=1){ if(t<o) red[t]+=red[t+o]; __syncthreads(); }
    if(t==0) out[b*2+0] = red[0]+cb[0];
    __syncthreads();
    red[t]=p1; __syncthreads();
    for(int o=128;o>0;o>>=1){ if(t<o) red[t]+=red[t+o]; __syncthreads(); }
    if(t==0) out[b*2+1] = red[0]+cb[1];
}

extern "C" void kernel_launch(void* const* d_in, const int* in_sizes, int n_in,
                              void* d_out, int out_size, void* d_ws, size_t ws_size,
                              hipStream_t stream) {
    const float* x          = (const float*)d_in[0];
    const int*   word_ids   = (const int*)  d_in[1];
    const int*   word_index = (const int*)  d_in[2];
    const float* table      = (const float*)d_in[3];
    const float* lam        = (const float*)d_in[4];
    const float* mu         = (const float*)d_in[5];
    const float* dt_w = (const float*)d_in[6];
    const float* dt_b = (const float*)d_in[7];
    const float* dr_w = (const float*)d_in[8];
    const float* dr_b = (const float*)d_in[9];
    const float* q_w  = (const float*)d_in[10];
    const float* q_b  = (const float*)d_in[11];
    const float* k_w  = (const float*)d_in[12];
    const float* k_b  = (const float*)d_in[13];
    const float* v_w  = (const float*)d_in[14];
    const float* v_b  = (const float*)d_in[15];
    const float* qi_w = (const float*)d_in[16];
    const float* qi_b = (const float*)d_in[17];
    const float* ki_w = (const float*)d_in[18];
    const float* ki_b = (const float*)d_in[19];
    const float* vi_w = (const float*)d_in[20];
    const float* vi_b = (const float*)d_in[21];
    const float* fus_w = (const float*)d_in[22];
    const float* fus_b = (const float*)d_in[23];
    const float* dense_w = (const float*)d_in[24];
    const float* dense_b = (const float*)d_in[25];
    const float* cls_w = (const float*)d_in[26];
    const float* cls_b = (const float*)d_in[27];
    float* out = (float*)d_out;

    char* w = (char*)d_ws;
    float* xmix   = (float*)(w + 0);          // 12,582,912 B (tbuf aliases here early)
    float* tbuf   = (float*)(w + 0);          // 6,291,456 B, dead before k_copy
    float* we     = (float*)(w + 12582912);   //  6,291,456 B
    float* scores = (float*)(w + 18874368);   //    393,216 B
    float* r      = (float*)(w + 19267584);   //    589,824 B
    float* cst    = (float*)(w + 19857408);   //      1,024 B
    float* sm     = (float*)(w + 19858432);   //     32,768 B
    int*   mic    = (int*)  (w + 19891200);   //      8,192 B
    int*   keep   = (int*)  (w + 19899392);   //     16,384 B
    float* cg     = (float*)(w + 19915776);   //    589,824 B
    float* cpart  = (float*)(w + 20505600);   //  4,718,592 B
    float* qpart  = (float*)(w + 25224192);   //    294,912 B
    float* q0g    = (float*)(w + 25519104);   //     49,152 B
    float* g      = (float*)(w + 25568256);   //     24,576 B
    float* fus    = (float*)(w + 25592832);   //     24,576 B
    float* part   = (float*)(w + 25617408);   //    147,456 B  (reused A/B/C) -> 25,764,864 total
    (void)ws_size; (void)in_sizes; (void)n_in; (void)out_size;

    // word embeddings (k_embed1 also zeroes keep in blocks 0..15)
    k_embed1<<<384, 256, 0, stream>>>(table, word_ids, dt_w, dt_b, tbuf, keep);
    k_embed2<<<384, 256, 0, stream>>>(tbuf, dr_w, dr_b, we);
    // cosine/softmax/mic + keep-mask scatter
    k_cos<<<512, 256, 0, stream>>>(x, word_index, we, sm, mic, keep);
    // x_mix construction (k_copy overwrites the tbuf alias only after tbuf is dead)
    k_copy<<<3072, 256, 0, stream>>>((const float4*)x, (float4*)xmix, NB*SS*HH/4);
    k_mix<<<NB*WW, 256, 0, stream>>>(x, word_index, we, sm, mic, lam, xmix);
    // attention (query row 0 only, rank-1 trick) — parallel q0/r chain
    k_q   <<<NB*3*KC, 256, 0, stream>>>(x, q_w, qi_w, qpart);
    k_qred<<<NB, 256, 0, stream>>>(qpart, q_b, qi_b, k_b, ki_b, q0g, cst);
    k_r   <<<NB*24*3, 256, 0, stream>>>(q0g, k_w, ki_w, r);
    k_scores<<<NB*SS, 256, 0, stream>>>(xmix, r, cst, keep, scores);
    k_softmax<<<NB*24, 256, 0, stream>>>(scores);
    k_cpart<<<NB*8, 256, 0, stream>>>(scores, xmix, cpart);
    k_credux<<<(NB*24*HH+255)/256, 256, 0, stream>>>(cpart, cg);
    // epilogue: K-chunked partial matvecs, deterministic reduces
    k_finA<<<NB*3*KC, 256, 0, stream>>>(cg, v_w, vi_w, mu, part);
    k_redG<<<24, 256, 0, stream>>>(part, v_b, vi_b, mu, g);
    k_finB<<<NB*3*KC, 256, 0, stream>>>(g, fus_w, part);
    k_redF<<<24, 256, 0, stream>>>(part, fus_b, fus);
    k_finC<<<NB*3*KC, 256, 0, stream>>>(fus, dense_w, part);
    k_finD<<<NB, 256, 0, stream>>>(part, dense_b, cls_w, cls_b, out);
}

// Round 5
// 466.899 us; speedup vs baseline: 2.5563x; 1.3067x over previous
//
#include <hip/hip_runtime.h>
#include <math.h>

#define NB 8
#define SS 512
#define HH 768
#define NHD 12
#define HDIM 64
#define DWD 300
#define WW 256
#define LL 4
#define KC 6          // K-chunks for 768-deep matvecs (128 each)

__device__ __forceinline__ float waveReduceSum(float v){
    #pragma unroll
    for(int o=32;o>0;o>>=1) v += __shfl_xor(v,o,64);
    return v;
}

// ==== Kernel 1: GEMM1 (384 blocks) + keep-zero (16) + k_q partials (144) ====
// grid 544
__global__ __launch_bounds__(256) void k_embed1f(const float* __restrict__ table,
        const int* __restrict__ ids, const float* __restrict__ Wm,
        const float* __restrict__ bias, float* __restrict__ out,
        int* __restrict__ keep,
        const float* __restrict__ x, const float* __restrict__ qw,
        const float* __restrict__ qiw, float* __restrict__ qpart){
    int bid = blockIdx.x;
    int t = threadIdx.x;
    if(bid >= 400){                 // ---- k_q rider: q0/qi0 partials
        int rb = bid - 400;         // 0..143
        int kc = rb % KC;
        int jt = (rb/KC) % 3;
        int b  = rb / (KC*3);
        int j = jt*256 + t;
        const float* x0 = x + (size_t)b*SS*HH;   // seq position 0 (never inside a word)
        int i0 = kc*128;
        float a1=0.f, a2=0.f;
        for(int i=i0;i<i0+128;i++){
            float xv = x0[i];
            a1 += xv*qw[(size_t)i*HH+j];
            a2 += xv*qiw[(size_t)i*HH+j];
        }
        qpart[(((size_t)kc*NB + b)*2 + 0)*HH + j] = a1;
        qpart[(((size_t)kc*NB + b)*2 + 1)*HH + j] = a2;
        return;
    }
    if(bid >= 384){                 // ---- keep-zero rider
        int i = (bid-384)*256 + t;
        if(i < NB*SS) keep[i] = 0;
        return;
    }
    // ---- GEMM1: t = tanh(table[ids] @ dt_w + dt_b)  (2048x300x768)
    const int K=300;
    __shared__ float As[16][68];
    __shared__ float Bs[16][68];
    int bx = bid % 12;              // N tile
    int by = bid / 12;              // M tile
    int m0 = by*64, n0 = bx*64;
    int tm = t>>4, tn = t&15;
    int lm = t>>2, lk = (t&3)*4;
    int bj = t&63, bk0 = (t>>6)*4;
    int row_id = ids[m0+lm];
    float acc[4][4] = {};
    for(int k0=0;k0<K;k0+=16){
        #pragma unroll
        for(int e=0;e<4;e++){
            int kk = k0+lk+e;
            As[lk+e][lm] = (kk<K)? table[(size_t)row_id*DWD + kk] : 0.f;
        }
        #pragma unroll
        for(int e=0;e<4;e++){
            int kk = k0+bk0+e;
            Bs[bk0+e][bj] = (kk<K)? Wm[(size_t)kk*HH + n0+bj] : 0.f;
        }
        __syncthreads();
        #pragma unroll
        for(int k=0;k<16;k++){
            float4 a = *(const float4*)&As[k][tm*4];
            float4 b = *(const float4*)&Bs[k][tn*4];
            acc[0][0]+=a.x*b.x; acc[0][1]+=a.x*b.y; acc[0][2]+=a.x*b.z; acc[0][3]+=a.x*b.w;
            acc[1][0]+=a.y*b.x; acc[1][1]+=a.y*b.y; acc[1][2]+=a.y*b.z; acc[1][3]+=a.y*b.w;
            acc[2][0]+=a.z*b.x; acc[2][1]+=a.z*b.y; acc[2][2]+=a.z*b.z; acc[2][3]+=a.z*b.w;
            acc[3][0]+=a.w*b.x; acc[3][1]+=a.w*b.y; acc[3][2]+=a.w*b.z; acc[3][3]+=a.w*b.w;
        }
        __syncthreads();
    }
    #pragma unroll
    for(int i=0;i<4;i++){
        int m = m0 + tm*4 + i;
        int n = n0 + tn*4;
        float4 o;
        o.x = tanhf(acc[i][0] + bias[n+0]);
        o.y = tanhf(acc[i][1] + bias[n+1]);
        o.z = tanhf(acc[i][2] + bias[n+2]);
        o.w = tanhf(acc[i][3] + bias[n+3]);
        *(float4*)&out[(size_t)m*HH + n] = o;
    }
}

// ==== Kernel 2: GEMM2 (384) + x->xmix copy (3072) + qred (8) ====
// grid 3464
__global__ __launch_bounds__(256) void k_embed2f(const float* __restrict__ A,
        const float* __restrict__ Wm, const float* __restrict__ bias,
        float* __restrict__ out,
        const float4* __restrict__ xin4, float4* __restrict__ xmix4,
        const float* __restrict__ qpart,
        const float* __restrict__ qb, const float* __restrict__ qib,
        const float* __restrict__ kb, const float* __restrict__ kib,
        float* __restrict__ q0g, float* __restrict__ cst){
    int bid = blockIdx.x;
    int t = threadIdx.x;
    if(bid >= 3456){                // ---- qred rider (8 blocks)
        int b = bid - 3456;
        __shared__ float q0s[HH], qi0s[HH];
        for(int j=t;j<HH;j+=256){
            float a1=qb[j], a2=qib[j];
            #pragma unroll
            for(int kc=0;kc<KC;kc++){
                a1 += qpart[(((size_t)kc*NB+b)*2+0)*HH+j];
                a2 += qpart[(((size_t)kc*NB+b)*2+1)*HH+j];
            }
            q0s[j]=a1; qi0s[j]=a2;
            q0g[((size_t)b*2+0)*HH+j]=a1;
            q0g[((size_t)b*2+1)*HH+j]=a2;
        }
        __syncthreads();
        if(t<24){
            int slot=t, h=slot%NHD;
            const float* Kb = (slot<NHD)? kb:kib;
            const float* Q  = (slot<NHD)? q0s:qi0s;
            float a=0.f;
            for(int j=0;j<HDIM;j++) a += Kb[h*HDIM+j]*Q[h*HDIM+j];
            cst[b*24+slot]=a;
        }
        return;
    }
    if(bid >= 384){                 // ---- copy rider (3072 blocks, exact cover)
        int i = (bid-384)*256 + t;
        xmix4[i] = xin4[i];
        return;
    }
    // ---- GEMM2: we = t @ dr_w + dr_b  (2048x768x768)
    __shared__ float As[16][68];
    __shared__ float Bs[16][68];
    int bx = bid % 12;
    int by = bid / 12;
    int m0 = by*64, n0 = bx*64;
    int tm = t>>4, tn = t&15;
    int lm = t>>2, lk = (t&3)*4;
    int bj = t&63, bk0 = (t>>6)*4;
    float acc[4][4] = {};
    for(int k0=0;k0<HH;k0+=16){
        float4 av = *(const float4*)&A[(size_t)(m0+lm)*HH + k0 + lk];
        As[lk+0][lm]=av.x; As[lk+1][lm]=av.y; As[lk+2][lm]=av.z; As[lk+3][lm]=av.w;
        #pragma unroll
        for(int e=0;e<4;e++)
            Bs[bk0+e][bj] = Wm[(size_t)(k0+bk0+e)*HH + n0 + bj];
        __syncthreads();
        #pragma unroll
        for(int k=0;k<16;k++){
            float4 a = *(const float4*)&As[k][tm*4];
            float4 b = *(const float4*)&Bs[k][tn*4];
            acc[0][0]+=a.x*b.x; acc[0][1]+=a.x*b.y; acc[0][2]+=a.x*b.z; acc[0][3]+=a.x*b.w;
            acc[1][0]+=a.y*b.x; acc[1][1]+=a.y*b.y; acc[1][2]+=a.y*b.z; acc[1][3]+=a.y*b.w;
            acc[2][0]+=a.z*b.x; acc[2][1]+=a.z*b.y; acc[2][2]+=a.z*b.z; acc[2][3]+=a.z*b.w;
            acc[3][0]+=a.w*b.x; acc[3][1]+=a.w*b.y; acc[3][2]+=a.w*b.z; acc[3][3]+=a.w*b.w;
        }
        __syncthreads();
    }
    #pragma unroll
    for(int i=0;i<4;i++){
        int m = m0 + tm*4 + i;
        int n = n0 + tn*4;
        float4 o;
        o.x = acc[i][0] + bias[n+0];
        o.y = acc[i][1] + bias[n+1];
        o.z = acc[i][2] + bias[n+2];
        o.w = acc[i][3] + bias[n+3];
        *(float4*)&out[(size_t)m*HH + n] = o;
    }
}

// ==== Kernel 3: per-word cos+softmax+mic+keep+mix (2048) + k_r (576) ====
// grid 2624
__global__ __launch_bounds__(256) void k_cosmix(const float* __restrict__ x,
        const int* __restrict__ wi, const float* __restrict__ we,
        const float* __restrict__ lam, int* __restrict__ keep,
        float* __restrict__ xmix,
        const float* __restrict__ q0g, const float* __restrict__ kw,
        const float* __restrict__ kiw, float* __restrict__ r){
    int bid = blockIdx.x;
    int t = threadIdx.x;
    if(bid >= 2048){                // ---- k_r rider (576 blocks)
        int rb = bid - 2048;
        int ct = rb % 3;
        int slot = (rb/3) % 24;
        int b = rb / 72;
        int h = slot % NHD;
        __shared__ float qs[HDIM];
        const float* Q = q0g + ((size_t)b*2 + (slot<NHD?0:1))*HH + h*HDIM;
        if(t<HDIM) qs[t] = Q[t];
        __syncthreads();
        const float* K = (slot<NHD)? kw : kiw;
        int c = ct*256 + t;
        const float4* K4 = (const float4*)(K + (size_t)c*HH + h*HDIM);
        const float4* q4 = (const float4*)qs;
        float a=0.f;
        #pragma unroll
        for(int j=0;j<16;j++){
            float4 kv=K4[j], qv=q4[j];
            a += kv.x*qv.x + kv.y*qv.y + kv.z*qv.z + kv.w*qv.w;
        }
        r[((size_t)(b*24+slot))*HH + c] = a;
        return;
    }
    // ---- per-word block: wave l handles row start+l
    int bw = bid;
    int b = bw >> 8;                // /WW
    int start = wi[bw*2+0];
    int end   = wi[bw*2+1];
    int n = end - start;
    if(n <= 0) return;
    __shared__ float weS[HH];
    __shared__ float xrow[LL][HH];
    __shared__ float cos_s[LL];
    int wv = t>>6, lane = t&63;
    const float* wer = we + (size_t)bw*HH;
    float wev[12];
    float wn = 0.f;
    #pragma unroll
    for(int i=0;i<12;i++){
        float v = wer[lane+64*i];
        wev[i]=v; wn += v*v;
        if(wv==0) weS[lane+64*i] = v;
    }
    wn = waveReduceSum(wn);
    if(wv < n){
        const float* xr = x + ((size_t)(b*SS + start + wv))*HH;
        float d=0.f, xs=0.f;
        #pragma unroll
        for(int i=0;i<12;i++){
            float xv = xr[lane+64*i];
            xrow[wv][lane+64*i] = xv;
            d += xv*wev[i]; xs += xv*xv;
        }
        d = waveReduceSum(d); xs = waveReduceSum(xs);
        if(lane==0) cos_s[wv] = d / sqrtf(xs*wn);
    } else {
        if(lane==0) cos_s[wv] = -1e9f;
    }
    __syncthreads();
    float c0=cos_s[0], c1=cos_s[1], c2=cos_s[2], c3=cos_s[3];
    float m = fmaxf(fmaxf(c0,c1),fmaxf(c2,c3));
    float e0 = (0<n)? expf(c0-m):0.f;
    float e1 = (1<n)? expf(c1-m):0.f;
    float e2 = (2<n)? expf(c2-m):0.f;
    float e3 = (3<n)? expf(c3-m):0.f;
    float inv = 1.f/(e0+e1+e2+e3);
    float s0=e0*inv, s1=e1*inv, s2=e2*inv, s3=e3*inv;
    int mic = 0; float bv = c0;
    if(c1 > bv){bv=c1;mic=1;}
    if(c2 > bv){bv=c2;mic=2;}
    if(c3 > bv){bv=c3;mic=3;}
    if(t==0) keep[b*SS + start + mic] = 1;
    float f = expf(lam[0] - 1.f);
    float a = (n>1)? (1.f-f)/(float)(n-1) : (1.f-f);
    for(int j=t; j<HH; j+=256){
        float wej = weS[j];
        float v0=0.f,v1=0.f,v2=0.f,v3=0.f;
        if(0<n) v0 = xrow[0][j] + s0*wej;
        if(1<n) v1 = xrow[1][j] + s1*wej;
        if(2<n) v2 = xrow[2][j] + s2*wej;
        if(3<n) v3 = xrow[3][j] + s3*wej;
        float sumx = v0+v1+v2+v3;
        float xm = (mic==0)?v0:(mic==1)?v1:(mic==2)?v2:v3;
        float mm = f*xm + a*(sumx-xm);   // mix_mic
        if(0<n) xmix[((size_t)(b*SS+start+0))*HH+j] = (0==mic)? (n==1? v0 : mm) : ((1.f-a)*v0 + a*xm);
        if(1<n) xmix[((size_t)(b*SS+start+1))*HH+j] = (1==mic)? mm : ((1.f-a)*v1 + a*xm);
        if(2<n) xmix[((size_t)(b*SS+start+2))*HH+j] = (2==mic)? mm : ((1.f-a)*v2 + a*xm);
        if(3<n) xmix[((size_t)(b*SS+start+3))*HH+j] = (3==mic)? mm : ((1.f-a)*v3 + a*xm);
    }
}

// ==== Kernel 4: scores[b,slot,s] = (x_mix[b,s]·r + cst)/8, keep-mask slots>=12 ====
__global__ __launch_bounds__(256) void k_scores(const float* __restrict__ xmix,
        const float* __restrict__ r, const float* __restrict__ cst,
        const int* __restrict__ keep, float* __restrict__ scores){
    int bs = blockIdx.x;
    int b = bs >> 9, s = bs & 511;
    __shared__ float xr[HH];
    for(int i=threadIdx.x;i<HH;i+=256) xr[i] = xmix[(size_t)bs*HH + i];
    __syncthreads();
    int wv = threadIdx.x>>6, lane = threadIdx.x&63;
    int kp = keep[b*SS + s];
    #pragma unroll
    for(int q=0;q<6;q++){
        int slot = wv*6 + q;
        const float* rr = r + ((size_t)(b*24+slot))*HH;
        float d = 0.f;
        #pragma unroll
        for(int i=0;i<12;i++) d += xr[lane+64*i]*rr[lane+64*i];
        d = waveReduceSum(d);
        if(lane==0){
            float sc = (d + cst[b*24+slot])*0.125f;
            if(slot>=12 && !kp) sc = -1e30f;
            scores[((size_t)(b*24+slot))*SS + s] = sc;
        }
    }
}

// ==== Kernel 5: per-(b,slot,jt) softmax + weighted row-sum -> cg  (576 blocks) ====
__global__ __launch_bounds__(256) void k_attn(const float* __restrict__ scores,
        const float* __restrict__ xmix, float* __restrict__ cg){
    int rb = blockIdx.x;
    int jt = rb % 3;
    int bslot = rb / 3;
    int b = bslot / 24, slot = bslot % 24;
    int t = threadIdx.x;
    __shared__ float p[SS];
    __shared__ float red[256];
    const float* srow = scores + (size_t)bslot*SS;
    float v0 = srow[t], v1 = srow[t+256];
    red[t] = fmaxf(v0,v1); __syncthreads();
    for(int o=128;o>0;o>>=1){ if(t<o) red[t] = fmaxf(red[t],red[t+o]); __syncthreads(); }
    float m = red[0]; __syncthreads();
    float e0 = expf(v0-m), e1 = expf(v1-m);
    red[t] = e0+e1; __syncthreads();
    for(int o=128;o>0;o>>=1){ if(t<o) red[t] += red[t+o]; __syncthreads(); }
    float inv = 1.f/red[0];
    p[t] = e0*inv; p[t+256] = e1*inv;
    __syncthreads();
    int j = jt*256 + t;
    const float* xb = xmix + (size_t)b*SS*HH + j;
    float a0 = 0.f;
    for(int s=0;s<SS;s++) a0 += p[s]*xb[(size_t)s*HH];
    cg[((size_t)bslot)*HH + j] = a0;
}

// ==== Kernel 6: stage A partials: mu*h1 + (1-mu)*h2 (no bias)  (144 blocks) ====
__global__ __launch_bounds__(256) void k_finA(const float* __restrict__ cg,
        const float* __restrict__ vw, const float* __restrict__ viw,
        const float* __restrict__ mu_, float* __restrict__ part){
    int kc = blockIdx.x % KC;
    int jt = (blockIdx.x/KC) % 3;
    int b  = blockIdx.x / (KC*3);
    int j = jt*256 + threadIdx.x;
    int h = j >> 6;                       // wave-uniform (j aligned to 64)
    float mu = mu_[0];
    const float* c1 = cg + ((size_t)(b*24+h))*HH;
    const float* c2 = cg + ((size_t)(b*24+12+h))*HH;
    int i0 = kc*128;
    float a1=0.f, a2=0.f;
    for(int i=i0;i<i0+128;i++){
        a1 += c1[i]*vw[(size_t)i*HH+j];
        a2 += c2[i]*viw[(size_t)i*HH+j];
    }
    part[((size_t)kc*NB+b)*HH + j] = mu*a1 + (1.f-mu)*a2;
}

// ==== Kernel 7: fused g-slice reduce + fus_w matvec  (144 blocks) ====
__global__ __launch_bounds__(256) void k_finB(const float* __restrict__ part1,
        const float* __restrict__ vb, const float* __restrict__ vib,
        const float* __restrict__ mu_, const float* __restrict__ fw,
        float* __restrict__ part2){
    int kc = blockIdx.x % KC;
    int jt = (blockIdx.x/KC) % 3;
    int b  = blockIdx.x / (KC*3);
    int i0 = kc*128;
    int t = threadIdx.x;
    __shared__ float gs[128];
    if(t < 128){
        int i = i0 + t;
        float mu = mu_[0];
        float s = mu*vb[i] + (1.f-mu)*vib[i];
        #pragma unroll
        for(int k2=0;k2<KC;k2++) s += part1[((size_t)k2*NB+b)*HH + i];
        gs[t] = s;
    }
    __syncthreads();
    int j = jt*256 + t;
    float a = 0.f;
    for(int k=0;k<128;k++) a += gs[k]*fw[(size_t)(i0+k)*HH + j];
    part2[((size_t)kc*NB+b)*HH + j] = a;
}

// ==== Kernel 8: fused fus-slice (tanh) + dense_w matvec  (144 blocks) ====
__global__ __launch_bounds__(256) void k_finC(const float* __restrict__ part2,
        const float* __restrict__ fb, const float* __restrict__ dw,
        float* __restrict__ part1){
    int kc = blockIdx.x % KC;
    int jt = (blockIdx.x/KC) % 3;
    int b  = blockIdx.x / (KC*3);
    int i0 = kc*128;
    int t = threadIdx.x;
    __shared__ float fs[128];
    if(t < 128){
        int i = i0 + t;
        float s = fb[i];
        #pragma unroll
        for(int k2=0;k2<KC;k2++) s += part2[((size_t)k2*NB+b)*HH + i];
        fs[t] = tanhf(s);
    }
    __syncthreads();
    int j = jt*256 + t;
    float a = 0.f;
    for(int k=0;k<128;k++) a += fs[k]*dw[(size_t)(i0+k)*HH + j];
    part1[((size_t)kc*NB+b)*HH + j] = a;
}

// ==== Kernel 9: pooled = tanh(sum + db); logits  (8 blocks) ====
__global__ __launch_bounds__(256) void k_finD(const float* __restrict__ part,
        const float* __restrict__ db, const float* __restrict__ cw,
        const float* __restrict__ cb, float* __restrict__ out){
    int b = blockIdx.x;
    int t = threadIdx.x;
    __shared__ float pooled[HH];
    __shared__ float red[256];
    for(int j=t;j<HH;j+=256){
        float s = db[j];
        #pragma unroll
        for(int kc=0;kc<KC;kc++) s += part[((size_t)kc*NB+b)*HH+j];
        pooled[j] = tanhf(s);
    }
    __syncthreads();
    float p0=0.f, p1=0.f;
    for(int i=t;i<HH;i+=256){ p0 += pooled[i]*cw[i*2+0]; p1 += pooled[i]*cw[i*2+1]; }
    red[t]=p0; __syncthreads();
    for(int o=128;o>0;o>>=1){ if(t<o) red[t]+=red[t+o]; __syncthreads(); }
    if(t==0) out[b*2+0] = red[0]+cb[0];
    __syncthreads();
    red[t]=p1; __syncthreads();
    for(int o=128;o>0;o>>=1){ if(t<o) red[t]+=red[t+o]; __syncthreads(); }
    if(t==0) out[b*2+1] = red[0]+cb[1];
}

extern "C" void kernel_launch(void* const* d_in, const int* in_sizes, int n_in,
                              void* d_out, int out_size, void* d_ws, size_t ws_size,
                              hipStream_t stream) {
    const float* x          = (const float*)d_in[0];
    const int*   word_ids   = (const int*)  d_in[1];
    const int*   word_index = (const int*)  d_in[2];
    const float* table      = (const float*)d_in[3];
    const float* lam        = (const float*)d_in[4];
    const float* mu         = (const float*)d_in[5];
    const float* dt_w = (const float*)d_in[6];
    const float* dt_b = (const float*)d_in[7];
    const float* dr_w = (const float*)d_in[8];
    const float* dr_b = (const float*)d_in[9];
    const float* q_w  = (const float*)d_in[10];
    const float* q_b  = (const float*)d_in[11];
    const float* k_w  = (const float*)d_in[12];
    const float* k_b  = (const float*)d_in[13];
    const float* v_w  = (const float*)d_in[14];
    const float* v_b  = (const float*)d_in[15];
    const float* qi_w = (const float*)d_in[16];
    const float* qi_b = (const float*)d_in[17];
    const float* ki_w = (const float*)d_in[18];
    const float* ki_b = (const float*)d_in[19];
    const float* vi_w = (const float*)d_in[20];
    const float* vi_b = (const float*)d_in[21];
    const float* fus_w = (const float*)d_in[22];
    const float* fus_b = (const float*)d_in[23];
    const float* dense_w = (const float*)d_in[24];
    const float* dense_b = (const float*)d_in[25];
    const float* cls_w = (const float*)d_in[26];
    const float* cls_b = (const float*)d_in[27];
    float* out = (float*)d_out;

    char* w = (char*)d_ws;
    float* xmix   = (float*)(w + 0);          // 12,582,912
    float* tbuf   = (float*)(w + 12582912);   //  6,291,456 (no longer aliases xmix:
                                              //  copy riders write xmix while gemm2 reads tbuf)
    float* we     = (float*)(w + 18874368);   //  6,291,456
    float* scores = (float*)(w + 25165824);   //    393,216
    float* r      = (float*)(w + 25559040);   //    589,824
    float* cst    = (float*)(w + 26148864);   //      1,024
    int*   keep   = (int*)  (w + 26149888);   //     16,384
    float* cg     = (float*)(w + 26166272);   //    589,824
    float* qpart  = (float*)(w + 26756096);   //    294,912
    float* q0g    = (float*)(w + 27051008);   //     49,152
    float* part1  = (float*)(w + 27100160);   //    147,456
    float* part2  = (float*)(w + 27247616);   //    147,456  -> total 27,395,072
    (void)ws_size; (void)in_sizes; (void)n_in; (void)out_size;

    // 1: embed GEMM1 + keep-zero + q-partials
    k_embed1f<<<544, 256, 0, stream>>>(table, word_ids, dt_w, dt_b, tbuf, keep,
                                       x, q_w, qi_w, qpart);
    // 2: embed GEMM2 + x->xmix copy + q-reduce/cst
    k_embed2f<<<3464, 256, 0, stream>>>(tbuf, dr_w, dr_b, we,
                                        (const float4*)x, (float4*)xmix,
                                        qpart, q_b, qi_b, k_b, ki_b, q0g, cst);
    // 3: per-word cos/softmax/mic/keep/mix + r-vectors
    k_cosmix<<<2624, 256, 0, stream>>>(x, word_index, we, lam, keep, xmix,
                                       q0g, k_w, ki_w, r);
    // 4: rank-1 attention scores
    k_scores<<<NB*SS, 256, 0, stream>>>(xmix, r, cst, keep, scores);
    // 5: softmax + weighted row-sum -> cg
    k_attn<<<NB*24*3, 256, 0, stream>>>(scores, xmix, cg);
    // 6-9: epilogue (K-chunked matvecs, fused slice-reduces)
    k_finA<<<NB*3*KC, 256, 0, stream>>>(cg, v_w, vi_w, mu, part1);
    k_finB<<<NB*3*KC, 256, 0, stream>>>(part1, v_b, vi_b, mu, fus_w, part2);
    k_finC<<<NB*3*KC, 256, 0, stream>>>(part2, fus_b, dense_w, part1);
    k_finD<<<NB, 256, 0, stream>>>(part1, dense_b, cls_w, cls_b, out);
}

// Round 7
// 446.723 us; speedup vs baseline: 2.6718x; 1.0452x over previous
//
#include <hip/hip_runtime.h>
#include <math.h>

#define NB 8
#define SS 512
#define HH 768
#define NHD 12
#define HDIM 64
#define DWD 300
#define WW 256
#define LL 4
#define KC 6          // K-chunks for 768-deep matvecs (128 each)

__device__ __forceinline__ float waveReduceSum(float v){
    #pragma unroll
    for(int o=32;o>0;o>>=1) v += __shfl_xor(v,o,64);
    return v;
}

// ==== Kernel 1: GEMM1 (384 blocks) + keep-zero (16) + k_q partials (144) ====
// grid 544.  GEMM1: t = tanh(table[ids] @ dt_w + dt_b)  (2048x300x768)
// double-buffered: prefetch tile k+1 into regs while computing tile k.
__global__ __launch_bounds__(256) void k_embed1f(const float* __restrict__ table,
        const int* __restrict__ ids, const float* __restrict__ Wm,
        const float* __restrict__ bias, float* __restrict__ out,
        int* __restrict__ keep,
        const float* __restrict__ x, const float* __restrict__ qw,
        const float* __restrict__ qiw, float* __restrict__ qpart){
    int bid = blockIdx.x;
    int t = threadIdx.x;
    if(bid >= 400){                 // ---- k_q rider: q0/qi0 partials
        int rb = bid - 400;         // 0..143
        int kc = rb % KC;
        int jt = (rb/KC) % 3;
        int b  = rb / (KC*3);
        int j = jt*256 + t;
        const float* x0 = x + (size_t)b*SS*HH;   // seq position 0 (never inside a word)
        int i0 = kc*128;
        float a1=0.f, a2=0.f;
        for(int i=i0;i<i0+128;i++){
            float xv = x0[i];
            a1 += xv*qw[(size_t)i*HH+j];
            a2 += xv*qiw[(size_t)i*HH+j];
        }
        qpart[(((size_t)kc*NB + b)*2 + 0)*HH + j] = a1;
        qpart[(((size_t)kc*NB + b)*2 + 1)*HH + j] = a2;
        return;
    }
    if(bid >= 384){                 // ---- keep-zero rider
        int i = (bid-384)*256 + t;
        if(i < NB*SS) keep[i] = 0;
        return;
    }
    const int K=300, NT=19;         // ceil(300/16)
    __shared__ float As[16][68];
    __shared__ float Bs[16][68];
    int bx = bid % 12;              // N tile
    int by = bid / 12;              // M tile
    int m0 = by*64, n0 = bx*64;
    int tm = t>>4, tn = t&15;
    int lm = t>>2, lk = (t&3)*4;    // A: row lm, k lk..lk+3
    int kk = t>>4, c4 = (t&15)*4;   // B: k-row kk, cols c4..c4+3
    int row_id = ids[m0+lm];
    const float* arow = table + (size_t)row_id*DWD;
    float acc[4][4] = {};
    float4 av, bv;
    // prefetch tile 0
    if(lk < K) av = *(const float4*)&arow[lk]; else av = make_float4(0,0,0,0);
    if(kk < K) bv = *(const float4*)&Wm[(size_t)kk*HH + n0 + c4]; else bv = make_float4(0,0,0,0);
    for(int kt=0;kt<NT;kt++){
        __syncthreads();
        As[lk+0][lm]=av.x; As[lk+1][lm]=av.y; As[lk+2][lm]=av.z; As[lk+3][lm]=av.w;
        *(float4*)&Bs[kk][c4] = bv;
        __syncthreads();
        if(kt+1 < NT){
            int k0 = (kt+1)*16;
            if(k0+lk < K) av = *(const float4*)&arow[k0+lk]; else av = make_float4(0,0,0,0);
            if(k0+kk < K) bv = *(const float4*)&Wm[(size_t)(k0+kk)*HH + n0 + c4]; else bv = make_float4(0,0,0,0);
        }
        #pragma unroll
        for(int k=0;k<16;k++){
            float4 a = *(const float4*)&As[k][tm*4];
            float4 b = *(const float4*)&Bs[k][tn*4];
            acc[0][0]+=a.x*b.x; acc[0][1]+=a.x*b.y; acc[0][2]+=a.x*b.z; acc[0][3]+=a.x*b.w;
            acc[1][0]+=a.y*b.x; acc[1][1]+=a.y*b.y; acc[1][2]+=a.y*b.z; acc[1][3]+=a.y*b.w;
            acc[2][0]+=a.z*b.x; acc[2][1]+=a.z*b.y; acc[2][2]+=a.z*b.z; acc[2][3]+=a.z*b.w;
            acc[3][0]+=a.w*b.x; acc[3][1]+=a.w*b.y; acc[3][2]+=a.w*b.z; acc[3][3]+=a.w*b.w;
        }
    }
    #pragma unroll
    for(int i=0;i<4;i++){
        int m = m0 + tm*4 + i;
        int n = n0 + tn*4;
        float4 o;
        o.x = tanhf(acc[i][0] + bias[n+0]);
        o.y = tanhf(acc[i][1] + bias[n+1]);
        o.z = tanhf(acc[i][2] + bias[n+2]);
        o.w = tanhf(acc[i][3] + bias[n+3]);
        *(float4*)&out[(size_t)m*HH + n] = o;
    }
}

// ==== Kernel 2: GEMM2 (384) + x->xmix copy (3072) + qred (8) ====
// grid 3464.  GEMM2: we = t @ dr_w + dr_b  (2048x768x768), double-buffered.
__global__ __launch_bounds__(256) void k_embed2f(const float* __restrict__ A,
        const float* __restrict__ Wm, const float* __restrict__ bias,
        float* __restrict__ out,
        const float4* __restrict__ xin4, float4* __restrict__ xmix4,
        const float* __restrict__ qpart,
        const float* __restrict__ qb, const float* __restrict__ qib,
        const float* __restrict__ kb, const float* __restrict__ kib,
        float* __restrict__ q0g, float* __restrict__ cst){
    int bid = blockIdx.x;
    int t = threadIdx.x;
    if(bid >= 3456){                // ---- qred rider (8 blocks)
        int b = bid - 3456;
        __shared__ float q0s[HH], qi0s[HH];
        for(int j=t;j<HH;j+=256){
            float a1=qb[j], a2=qib[j];
            #pragma unroll
            for(int kc=0;kc<KC;kc++){
                a1 += qpart[(((size_t)kc*NB+b)*2+0)*HH+j];
                a2 += qpart[(((size_t)kc*NB+b)*2+1)*HH+j];
            }
            q0s[j]=a1; qi0s[j]=a2;
            q0g[((size_t)b*2+0)*HH+j]=a1;
            q0g[((size_t)b*2+1)*HH+j]=a2;
        }
        __syncthreads();
        if(t<24){
            int slot=t, h=slot%NHD;
            const float* Kb = (slot<NHD)? kb:kib;
            const float* Q  = (slot<NHD)? q0s:qi0s;
            float a=0.f;
            for(int j=0;j<HDIM;j++) a += Kb[h*HDIM+j]*Q[h*HDIM+j];
            cst[b*24+slot]=a;
        }
        return;
    }
    if(bid >= 384){                 // ---- copy rider (3072 blocks, exact cover)
        int i = (bid-384)*256 + t;
        xmix4[i] = xin4[i];
        return;
    }
    const int NT = 48;              // 768/16
    __shared__ float As[16][68];
    __shared__ float Bs[16][68];
    int bx = bid % 12;
    int by = bid / 12;
    int m0 = by*64, n0 = bx*64;
    int tm = t>>4, tn = t&15;
    int lm = t>>2, lk = (t&3)*4;
    int kk = t>>4, c4 = (t&15)*4;
    const float* arow = A + (size_t)(m0+lm)*HH;
    float acc[4][4] = {};
    float4 av = *(const float4*)&arow[lk];
    float4 bv = *(const float4*)&Wm[(size_t)kk*HH + n0 + c4];
    for(int kt=0;kt<NT;kt++){
        __syncthreads();
        As[lk+0][lm]=av.x; As[lk+1][lm]=av.y; As[lk+2][lm]=av.z; As[lk+3][lm]=av.w;
        *(float4*)&Bs[kk][c4] = bv;
        __syncthreads();
        if(kt+1 < NT){
            int k0 = (kt+1)*16;
            av = *(const float4*)&arow[k0+lk];
            bv = *(const float4*)&Wm[(size_t)(k0+kk)*HH + n0 + c4];
        }
        #pragma unroll
        for(int k=0;k<16;k++){
            float4 a = *(const float4*)&As[k][tm*4];
            float4 b = *(const float4*)&Bs[k][tn*4];
            acc[0][0]+=a.x*b.x; acc[0][1]+=a.x*b.y; acc[0][2]+=a.x*b.z; acc[0][3]+=a.x*b.w;
            acc[1][0]+=a.y*b.x; acc[1][1]+=a.y*b.y; acc[1][2]+=a.y*b.z; acc[1][3]+=a.y*b.w;
            acc[2][0]+=a.z*b.x; acc[2][1]+=a.z*b.y; acc[2][2]+=a.z*b.z; acc[2][3]+=a.z*b.w;
            acc[3][0]+=a.w*b.x; acc[3][1]+=a.w*b.y; acc[3][2]+=a.w*b.z; acc[3][3]+=a.w*b.w;
        }
    }
    #pragma unroll
    for(int i=0;i<4;i++){
        int m = m0 + tm*4 + i;
        int n = n0 + tn*4;
        float4 o;
        o.x = acc[i][0] + bias[n+0];
        o.y = acc[i][1] + bias[n+1];
        o.z = acc[i][2] + bias[n+2];
        o.w = acc[i][3] + bias[n+3];
        *(float4*)&out[(size_t)m*HH + n] = o;
    }
}

// ==== Kernel 3: per-word cos+softmax+mic+keep+mix (2048) + k_r (576) ====
// grid 2624
__global__ __launch_bounds__(256) void k_cosmix(const float* __restrict__ x,
        const int* __restrict__ wi, const float* __restrict__ we,
        const float* __restrict__ lam, int* __restrict__ keep,
        float* __restrict__ xmix,
        const float* __restrict__ q0g, const float* __restrict__ kw,
        const float* __restrict__ kiw, float* __restrict__ r){
    int bid = blockIdx.x;
    int t = threadIdx.x;
    if(bid >= 2048){                // ---- k_r rider (576 blocks)
        int rb = bid - 2048;
        int ct = rb % 3;
        int slot = (rb/3) % 24;
        int b = rb / 72;
        int h = slot % NHD;
        __shared__ float qs[HDIM];
        const float* Q = q0g + ((size_t)b*2 + (slot<NHD?0:1))*HH + h*HDIM;
        if(t<HDIM) qs[t] = Q[t];
        __syncthreads();
        const float* K = (slot<NHD)? kw : kiw;
        int c = ct*256 + t;
        const float4* K4 = (const float4*)(K + (size_t)c*HH + h*HDIM);
        const float4* q4 = (const float4*)qs;
        float a=0.f;
        #pragma unroll
        for(int j=0;j<16;j++){
            float4 kv=K4[j], qv=q4[j];
            a += kv.x*qv.x + kv.y*qv.y + kv.z*qv.z + kv.w*qv.w;
        }
        r[((size_t)(b*24+slot))*HH + c] = a;
        return;
    }
    // ---- per-word block: wave l handles row start+l
    int bw = bid;
    int b = bw >> 8;                // /WW
    int start = wi[bw*2+0];
    int end   = wi[bw*2+1];
    int n = end - start;
    if(n <= 0) return;
    __shared__ float weS[HH];
    __shared__ float xrow[LL][HH];
    __shared__ float cos_s[LL];
    int wv = t>>6, lane = t&63;
    const float* wer = we + (size_t)bw*HH;
    float wev[12];
    float wn = 0.f;
    #pragma unroll
    for(int i=0;i<12;i++){
        float v = wer[lane+64*i];
        wev[i]=v; wn += v*v;
        if(wv==0) weS[lane+64*i] = v;
    }
    wn = waveReduceSum(wn);
    if(wv < n){
        const float* xr = x + ((size_t)(b*SS + start + wv))*HH;
        float d=0.f, xs=0.f;
        #pragma unroll
        for(int i=0;i<12;i++){
            float xv = xr[lane+64*i];
            xrow[wv][lane+64*i] = xv;
            d += xv*wev[i]; xs += xv*xv;
        }
        d = waveReduceSum(d); xs = waveReduceSum(xs);
        if(lane==0) cos_s[wv] = d / sqrtf(xs*wn);
    } else {
        if(lane==0) cos_s[wv] = -1e9f;
    }
    __syncthreads();
    float c0=cos_s[0], c1=cos_s[1], c2=cos_s[2], c3=cos_s[3];
    float m = fmaxf(fmaxf(c0,c1),fmaxf(c2,c3));
    float e0 = (0<n)? expf(c0-m):0.f;
    float e1 = (1<n)? expf(c1-m):0.f;
    float e2 = (2<n)? expf(c2-m):0.f;
    float e3 = (3<n)? expf(c3-m):0.f;
    float inv = 1.f/(e0+e1+e2+e3);
    float s0=e0*inv, s1=e1*inv, s2=e2*inv, s3=e3*inv;
    int mic = 0; float bv = c0;
    if(c1 > bv){bv=c1;mic=1;}
    if(c2 > bv){bv=c2;mic=2;}
    if(c3 > bv){bv=c3;mic=3;}
    if(t==0) keep[b*SS + start + mic] = 1;
    float f = expf(lam[0] - 1.f);
    float a = (n>1)? (1.f-f)/(float)(n-1) : (1.f-f);
    for(int j=t; j<HH; j+=256){
        float wej = weS[j];
        float v0=0.f,v1=0.f,v2=0.f,v3=0.f;
        if(0<n) v0 = xrow[0][j] + s0*wej;
        if(1<n) v1 = xrow[1][j] + s1*wej;
        if(2<n) v2 = xrow[2][j] + s2*wej;
        if(3<n) v3 = xrow[3][j] + s3*wej;
        float sumx = v0+v1+v2+v3;
        float xm = (mic==0)?v0:(mic==1)?v1:(mic==2)?v2:v3;
        float mm = f*xm + a*(sumx-xm);   // mix_mic
        if(0<n) xmix[((size_t)(b*SS+start+0))*HH+j] = (0==mic)? (n==1? v0 : mm) : ((1.f-a)*v0 + a*xm);
        if(1<n) xmix[((size_t)(b*SS+start+1))*HH+j] = (1==mic)? mm : ((1.f-a)*v1 + a*xm);
        if(2<n) xmix[((size_t)(b*SS+start+2))*HH+j] = (2==mic)? mm : ((1.f-a)*v2 + a*xm);
        if(3<n) xmix[((size_t)(b*SS+start+3))*HH+j] = (3==mic)? mm : ((1.f-a)*v3 + a*xm);
    }
}

// ==== Kernel 4: scores[b,slot,s] = (x_mix[b,s]·r + cst)/8, keep-mask slots>=12 ====
__global__ __launch_bounds__(256) void k_scores(const float* __restrict__ xmix,
        const float* __restrict__ r, const float* __restrict__ cst,
        const int* __restrict__ keep, float* __restrict__ scores){
    int bs = blockIdx.x;
    int b = bs >> 9, s = bs & 511;
    __shared__ float xr[HH];
    for(int i=threadIdx.x;i<HH;i+=256) xr[i] = xmix[(size_t)bs*HH + i];
    __syncthreads();
    int wv = threadIdx.x>>6, lane = threadIdx.x&63;
    int kp = keep[b*SS + s];
    #pragma unroll
    for(int q=0;q<6;q++){
        int slot = wv*6 + q;
        const float* rr = r + ((size_t)(b*24+slot))*HH;
        float d = 0.f;
        #pragma unroll
        for(int i=0;i<12;i++) d += xr[lane+64*i]*rr[lane+64*i];
        d = waveReduceSum(d);
        if(lane==0){
            float sc = (d + cst[b*24+slot])*0.125f;
            if(slot>=12 && !kp) sc = -1e30f;
            scores[((size_t)(b*24+slot))*SS + s] = sc;
        }
    }
}

// ==== Kernel 5: per-(b,slot,jt) softmax + weighted row-sum -> cg  (576 blocks) ====
__global__ __launch_bounds__(256) void k_attn(const float* __restrict__ scores,
        const float* __restrict__ xmix, float* __restrict__ cg){
    int rb = blockIdx.x;
    int jt = rb % 3;
    int bslot = rb / 3;
    int b = bslot / 24, slot = bslot % 24;
    int t = threadIdx.x;
    __shared__ float p[SS];
    __shared__ float red[256];
    const float* srow = scores + (size_t)bslot*SS;
    float v0 = srow[t], v1 = srow[t+256];
    red[t] = fmaxf(v0,v1); __syncthreads();
    for(int o=128;o>0;o>>=1){ if(t<o) red[t] = fmaxf(red[t],red[t+o]); __syncthreads(); }
    float m = red[0]; __syncthreads();
    float e0 = expf(v0-m), e1 = expf(v1-m);
    red[t] = e0+e1; __syncthreads();
    for(int o=128;o>0;o>>=1){ if(t<o) red[t] += red[t+o]; __syncthreads(); }
    float inv = 1.f/red[0];
    p[t] = e0*inv; p[t+256] = e1*inv;
    __syncthreads();
    int j = jt*256 + t;
    const float* xb = xmix + (size_t)b*SS*HH + j;
    float a0 = 0.f;
    for(int s=0;s<SS;s++) a0 += p[s]*xb[(size_t)s*HH];
    cg[((size_t)bslot)*HH + j] = a0;
    (void)slot;
}

// ==== Kernel 6: stage A partials: mu*h1 + (1-mu)*h2 (no bias)  (144 blocks) ====
__global__ __launch_bounds__(256) void k_finA(const float* __restrict__ cg,
        const float* __restrict__ vw, const float* __restrict__ viw,
        const float* __restrict__ mu_, float* __restrict__ part){
    int kc = blockIdx.x % KC;
    int jt = (blockIdx.x/KC) % 3;
    int b  = blockIdx.x / (KC*3);
    int j = jt*256 + threadIdx.x;
    int h = j >> 6;                       // wave-uniform (j aligned to 64)
    float mu = mu_[0];
    const float* c1 = cg + ((size_t)(b*24+h))*HH;
    const float* c2 = cg + ((size_t)(b*24+12+h))*HH;
    int i0 = kc*128;
    float a1=0.f, a2=0.f;
    for(int i=i0;i<i0+128;i++){
        a1 += c1[i]*vw[(size_t)i*HH+j];
        a2 += c2[i]*viw[(size_t)i*HH+j];
    }
    part[((size_t)kc*NB+b)*HH + j] = mu*a1 + (1.f-mu)*a2;
}

// ==== Kernel 7: fused g-slice reduce + fus_w matvec  (144 blocks) ====
__global__ __launch_bounds__(256) void k_finB(const float* __restrict__ part1,
        const float* __restrict__ vb, const float* __restrict__ vib,
        const float* __restrict__ mu_, const float* __restrict__ fw,
        float* __restrict__ part2){
    int kc = blockIdx.x % KC;
    int jt = (blockIdx.x/KC) % 3;
    int b  = blockIdx.x / (KC*3);
    int i0 = kc*128;
    int t = threadIdx.x;
    __shared__ float gs[128];
    if(t < 128){
        int i = i0 + t;
        float mu = mu_[0];
        float s = mu*vb[i] + (1.f-mu)*vib[i];
        #pragma unroll
        for(int k2=0;k2<KC;k2++) s += part1[((size_t)k2*NB+b)*HH + i];
        gs[t] = s;
    }
    __syncthreads();
    int j = jt*256 + t;
    float a = 0.f;
    for(int k=0;k<128;k++) a += gs[k]*fw[(size_t)(i0+k)*HH + j];
    part2[((size_t)kc*NB+b)*HH + j] = a;
}

// ==== Kernel 8: fused fus-slice (tanh) + dense_w matvec  (144 blocks) ====
__global__ __launch_bounds__(256) void k_finC(const float* __restrict__ part2,
        const float* __restrict__ fb, const float* __restrict__ dw,
        float* __restrict__ part1){
    int kc = blockIdx.x % KC;
    int jt = (blockIdx.x/KC) % 3;
    int b  = blockIdx.x / (KC*3);
    int i0 = kc*128;
    int t = threadIdx.x;
    __shared__ float fs[128];
    if(t < 128){
        int i = i0 + t;
        float s = fb[i];
        #pragma unroll
        for(int k2=0;k2<KC;k2++) s += part2[((size_t)k2*NB+b)*HH + i];
        fs[t] = tanhf(s);
    }
    __syncthreads();
    int j = jt*256 + t;
    float a = 0.f;
    for(int k=0;k<128;k++) a += fs[k]*dw[(size_t)(i0+k)*HH + j];
    part1[((size_t)kc*NB+b)*HH + j] = a;
}

// ==== Kernel 9: pooled = tanh(sum + db); logits  (8 blocks) ====
__global__ __launch_bounds__(256) void k_finD(const float* __restrict__ part,
        const float* __restrict__ db, const float* __restrict__ cw,
        const float* __restrict__ cb, float* __restrict__ out){
    int b = blockIdx.x;
    int t = threadIdx.x;
    __shared__ float pooled[HH];
    __shared__ float red[256];
    for(int j=t;j<HH;j+=256){
        float s = db[j];
        #pragma unroll
        for(int kc=0;kc<KC;kc++) s += part[((size_t)kc*NB+b)*HH+j];
        pooled[j] = tanhf(s);
    }
    __syncthreads();
    float p0=0.f, p1=0.f;
    for(int i=t;i<HH;i+=256){ p0 += pooled[i]*cw[i*2+0]; p1 += pooled[i]*cw[i*2+1]; }
    red[t]=p0; __syncthreads();
    for(int o=128;o>0;o>>=1){ if(t<o) red[t]+=red[t+o]; __syncthreads(); }
    if(t==0) out[b*2+0] = red[0]+cb[0];
    __syncthreads();
    red[t]=p1; __syncthreads();
    for(int o=128;o>0;o>>=1){ if(t<o) red[t]+=red[t+o]; __syncthreads(); }
    if(t==0) out[b*2+1] = red[0]+cb[1];
}

extern "C" void kernel_launch(void* const* d_in, const int* in_sizes, int n_in,
                              void* d_out, int out_size, void* d_ws, size_t ws_size,
                              hipStream_t stream) {
    const float* x          = (const float*)d_in[0];
    const int*   word_ids   = (const int*)  d_in[1];
    const int*   word_index = (const int*)  d_in[2];
    const float* table      = (const float*)d_in[3];
    const float* lam        = (const float*)d_in[4];
    const float* mu         = (const float*)d_in[5];
    const float* dt_w = (const float*)d_in[6];
    const float* dt_b = (const float*)d_in[7];
    const float* dr_w = (const float*)d_in[8];
    const float* dr_b = (const float*)d_in[9];
    const float* q_w  = (const float*)d_in[10];
    const float* q_b  = (const float*)d_in[11];
    const float* k_w  = (const float*)d_in[12];
    const float* k_b  = (const float*)d_in[13];
    const float* v_w  = (const float*)d_in[14];
    const float* v_b  = (const float*)d_in[15];
    const float* qi_w = (const float*)d_in[16];
    const float* qi_b = (const float*)d_in[17];
    const float* ki_w = (const float*)d_in[18];
    const float* ki_b = (const float*)d_in[19];
    const float* vi_w = (const float*)d_in[20];
    const float* vi_b = (const float*)d_in[21];
    const float* fus_w = (const float*)d_in[22];
    const float* fus_b = (const float*)d_in[23];
    const float* dense_w = (const float*)d_in[24];
    const float* dense_b = (const float*)d_in[25];
    const float* cls_w = (const float*)d_in[26];
    const float* cls_b = (const float*)d_in[27];
    float* out = (float*)d_out;

    char* w = (char*)d_ws;
    float* xmix   = (float*)(w + 0);          // 12,582,912
    float* tbuf   = (float*)(w + 12582912);   //  6,291,456 (distinct from xmix:
                                              //  copy riders write xmix while gemm2 reads tbuf)
    float* we     = (float*)(w + 18874368);   //  6,291,456
    float* scores = (float*)(w + 25165824);   //    393,216
    float* r      = (float*)(w + 25559040);   //    589,824
    float* cst    = (float*)(w + 26148864);   //      1,024
    int*   keep   = (int*)  (w + 26149888);   //     16,384
    float* cg     = (float*)(w + 26166272);   //    589,824
    float* qpart  = (float*)(w + 26756096);   //    294,912
    float* q0g    = (float*)(w + 27051008);   //     49,152
    float* part1  = (float*)(w + 27100160);   //    147,456
    float* part2  = (float*)(w + 27247616);   //    147,456  -> total 27,395,072
    (void)ws_size; (void)in_sizes; (void)n_in; (void)out_size;

    // 1: embed GEMM1 (dbuf) + keep-zero + q-partials
    k_embed1f<<<544, 256, 0, stream>>>(table, word_ids, dt_w, dt_b, tbuf, keep,
                                       x, q_w, qi_w, qpart);
    // 2: embed GEMM2 (dbuf) + x->xmix copy + q-reduce/cst
    k_embed2f<<<3464, 256, 0, stream>>>(tbuf, dr_w, dr_b, we,
                                        (const float4*)x, (float4*)xmix,
                                        qpart, q_b, qi_b, k_b, ki_b, q0g, cst);
    // 3: per-word cos/softmax/mic/keep/mix + r-vectors
    k_cosmix<<<2624, 256, 0, stream>>>(x, word_index, we, lam, keep, xmix,
                                       q0g, k_w, ki_w, r);
    // 4: rank-1 attention scores
    k_scores<<<NB*SS, 256, 0, stream>>>(xmix, r, cst, keep, scores);
    // 5: softmax + weighted row-sum -> cg
    k_attn<<<NB*24*3, 256, 0, stream>>>(scores, xmix, cg);
    // 6-9: epilogue (K-chunked matvecs, fused slice-reduces)
    k_finA<<<NB*3*KC, 256, 0, stream>>>(cg, v_w, vi_w, mu, part1);
    k_finB<<<NB*3*KC, 256, 0, stream>>>(part1, v_b, vi_b, mu, fus_w, part2);
    k_finC<<<NB*3*KC, 256, 0, stream>>>(part2, fus_b, dense_w, part1);
    k_finD<<<NB, 256, 0, stream>>>(part1, dense_b, cls_w, cls_b, out);
}